// Round 15
// baseline (582.173 us; speedup 1.0000x reference)
//
#include <hip/hip_runtime.h>

#define NN 50000
#define NE 800000
#define FBLK 8192
#define BKT 256
#define NCPY 8

typedef unsigned short u16;
typedef unsigned int u32;

typedef float f32x4 __attribute__((ext_vector_type(4)));
typedef __bf16 bf16x8 __attribute__((ext_vector_type(8)));
static_assert(sizeof(bf16x8) == 16, "bf16x8 must be 16B");

__device__ __forceinline__ float bf2f(u16 u) {
    u32 x = ((u32)u) << 16;
    return __uint_as_float(x);
}
__device__ __forceinline__ u16 f2bf(float f) {
    u32 x = __float_as_uint(f);
    u32 r = (x + 0x7fffu + ((x >> 16) & 1u)) >> 16;  // round-nearest-even
    return (u16)r;
}
__device__ __forceinline__ u32 pack2(float a, float b) {
    return (u32)f2bf(a) | ((u32)f2bf(b) << 16);
}
// fp16 (IEEE half) pack/unpack: H tensor is fp16 (2^-11 rel err vs bf16's 2^-8).
__device__ __forceinline__ u16 f2h(float f) {
    _Float16 h = (_Float16)f;
    union { _Float16 h; u16 u; } c; c.h = h;
    return c.u;
}
__device__ __forceinline__ float h2f(u16 u) {
    union { u16 u; _Float16 h; } c; c.u = u;
    return (float)c.h;
}
__device__ __forceinline__ uint4 packu4(const u16* h) {
    uint4 u;
    u.x = (u32)h[0] | ((u32)h[1] << 16);
    u.y = (u32)h[2] | ((u32)h[3] << 16);
    u.z = (u32)h[4] | ((u32)h[5] << 16);
    u.w = (u32)h[6] | ((u32)h[7] << 16);
    return u;
}
__device__ __forceinline__ float ldf(const void* p, size_t idx, int mode) {
    return mode ? bf2f(((const u16*)p)[idx]) : ((const float*)p)[idx];
}
__device__ __forceinline__ float lrelu(float x) { return x > 0.f ? x : 0.2f * x; }

// D = A.B + C ; A/B frags: 8 contiguous k per lane (k-group = lane>>4), lane&15 = row(A)/col(B)
// D: col = lane&15, row = (lane>>4)*4 + reg   [measured m89/m91]
__device__ __forceinline__ f32x4 mfma16(uint4 a, uint4 b, f32x4 c) {
    union { uint4 u; bf16x8 b; } ua, ub;
    ua.u = a; ub.u = b;
    return __builtin_amdgcn_mfma_f32_16x16x32_bf16(ua.b, ub.b, c, 0, 0, 0);
}

// ---------------- diagnostics ----------------
__global__ void k_tracer(float* out, float v) {
    if (threadIdx.x == 0 && blockIdx.x == 0) out[0] = v;
}

// ---------------- dtype detect (0 = f32 inputs, 1 = bf16 inputs) ----------------
__global__ void k_detect(const u16* __restrict__ fvs, int* __restrict__ mode) {
    __shared__ int cnt[256];
    int t = threadIdx.x;
    int bad = 0;
    for (int i = 0; i < 16; i++) {
        u16 u = fvs[(size_t)(t * 16 + i) * 2];
        int e = (u >> 7) & 0xff;
        if (e == 255 || e >= 134 || e <= 100) bad++;
    }
    cnt[t] = bad;
    __syncthreads();
    for (int d = 128; d; d >>= 1) {
        if (t < d) cnt[t] += cnt[t + d];
        __syncthreads();
    }
    if (t == 0) *mode = (cnt[0] > 2048) ? 0 : 1;
}

// ---------------- CSR build ----------------
__global__ void k_hist(const int* __restrict__ dst, int* __restrict__ cnt, int E) {
    int e = blockIdx.x * blockDim.x + threadIdx.x;
    if (e < E) atomicAdd(&cnt[dst[e]], 1);
}

// Multi-block scan, 2048 elems/block (8/thread via int4).
__global__ void k_scan1(const int* __restrict__ cnt, int* __restrict__ off,
                        int* __restrict__ bsum, int N) {
    __shared__ int wsum[4];
    int t = threadIdx.x;
    int base = blockIdx.x * 2048 + t * 8;
    int e[8];
    if (base + 8 <= N) {
        int4 v0 = *(const int4*)&cnt[base];
        int4 v1 = *(const int4*)&cnt[base + 4];
        e[0] = v0.x; e[1] = v0.y; e[2] = v0.z; e[3] = v0.w;
        e[4] = v1.x; e[5] = v1.y; e[6] = v1.z; e[7] = v1.w;
    } else {
#pragma unroll
        for (int i = 0; i < 8; i++) e[i] = (base + i < N) ? cnt[base + i] : 0;
    }
    int s = 0;
    int ps[8];
#pragma unroll
    for (int i = 0; i < 8; i++) { ps[i] = s; s += e[i]; }
    int lane = t & 63, wv = t >> 6;
    int sc = s;
#pragma unroll
    for (int o = 1; o < 64; o <<= 1) {
        int u = __shfl_up(sc, o, 64);
        if (lane >= o) sc += u;
    }
    if (lane == 63) wsum[wv] = sc;
    __syncthreads();
    int woff = 0;
    for (int w = 0; w < wv; w++) woff += wsum[w];
    int ex = woff + sc - s;   // exclusive prefix of this thread within block
#pragma unroll
    for (int i = 0; i < 8; i++) ps[i] += ex;
    if (base + 8 <= N) {
        *(int4*)&off[base] = make_int4(ps[0], ps[1], ps[2], ps[3]);
        *(int4*)&off[base + 4] = make_int4(ps[4], ps[5], ps[6], ps[7]);
    } else {
#pragma unroll
        for (int i = 0; i < 8; i++)
            if (base + i < N) off[base + i] = ps[i];
    }
    if (t == 255) bsum[blockIdx.x] = woff + sc;   // block total
}

__global__ void k_scan2(const int* __restrict__ bsum, int* __restrict__ off,
                        int N, int nb) {
    int b = blockIdx.x, t = threadIdx.x;
    int boff = 0;
    for (int i = 0; i < b; i++) boff += bsum[i];   // uniform, <=24 iters
    int base = b * 2048 + t * 8;
    if (b > 0) {
        if (base + 8 <= N) {
            int4 a = *(int4*)&off[base];
            int4 c = *(int4*)&off[base + 4];
            a.x += boff; a.y += boff; a.z += boff; a.w += boff;
            c.x += boff; c.y += boff; c.z += boff; c.w += boff;
            *(int4*)&off[base] = a;
            *(int4*)&off[base + 4] = c;
        } else {
#pragma unroll
            for (int i = 0; i < 8; i++)
                if (base + i < N) off[base + i] += boff;
        }
    }
    if (b == nb - 1 && t == 255) off[N] = boff + bsum[b];
}

// ---- CSR fill via two-pass LDS multisplit ----
__global__ void k_binit(const int* __restrict__ off, int* __restrict__ bcur, int nbk) {
    int b = threadIdx.x;
    if (b < nbk) bcur[b] = off[b * BKT];
    else if (b < 256) bcur[b] = 0;
}

__launch_bounds__(256)
__global__ void k_fillA(const int* __restrict__ src, const int* __restrict__ dst,
                        int* __restrict__ bcur, u32* __restrict__ tmp, int E) {
    __shared__ int hist[256];
    __shared__ int lbase[256];
    __shared__ int gbase[256];
    __shared__ int lcur[256];
    __shared__ u32 outrec[FBLK];
    __shared__ unsigned char bslot[FBLK];
    int t = threadIdx.x;
    int e0 = blockIdx.x * FBLK;
    int bn = min(E - e0, FBLK);
    hist[t] = 0;
    __syncthreads();
    for (int i = t; i < bn; i += 256)
        atomicAdd(&hist[dst[e0 + i] >> 8], 1);
    __syncthreads();
    if (t == 0) {
        int run = 0;
        for (int b = 0; b < 256; b++) { lbase[b] = run; run += hist[b]; }
    }
    __syncthreads();
    lcur[t] = lbase[t];
    gbase[t] = hist[t] ? atomicAdd(&bcur[t], hist[t]) : 0;
    __syncthreads();
    for (int i = t; i < bn; i += 256) {
        int d = dst[e0 + i];
        int s = src[e0 + i];
        int b = d >> 8;
        int slot = atomicAdd(&lcur[b], 1);
        outrec[slot] = (u32)s | ((u32)(d & 255) << 24);   // src < 2^24
        bslot[slot] = (unsigned char)b;
    }
    __syncthreads();
    for (int i = t; i < bn; i += 256) {
        int b = bslot[i];
        tmp[gbase[b] + (i - lbase[b])] = outrec[i];       // contiguous bucket runs
    }
}

__launch_bounds__(256)
__global__ void k_fillB(const int* __restrict__ off, const u32* __restrict__ tmp,
                        int* __restrict__ ssrc, int N) {
    __shared__ int lcur[BKT];
    __shared__ u32 outv[FBLK];
    int b = blockIdx.x, t = threadIdx.x;
    int n0 = b * BKT;
    int nn = min(N - n0, BKT);
    int nbeg = off[n0], nend = off[n0 + nn];
    int sz = nend - nbeg;
    for (int i = t; i < nn; i += 256) lcur[i] = off[n0 + i] - nbeg;
    __syncthreads();
    if (sz <= FBLK) {
        for (int i = t; i < sz; i += 256) {
            u32 r = tmp[nbeg + i];
            int slot = atomicAdd(&lcur[r >> 24], 1);
            outv[slot] = r & 0x00FFFFFFu;
        }
        __syncthreads();
        for (int i = t; i < sz; i += 256)
            ssrc[nbeg + i] = (int)outv[i];
    } else {  // bucket overflow fallback (correctness only)
        for (int i = t; i < sz; i += 256) {
            u32 r = tmp[nbeg + i];
            int slot = atomicAdd(&lcur[r >> 24], 1);
            ssrc[nbeg + slot] = (int)(r & 0x00FFFFFFu);
        }
    }
}

// ---------------- init: hp = bf16(pos) ----------------
__global__ void k_init(const void* __restrict__ pos, u16* __restrict__ hp,
                       const int* __restrict__ dmode, int n64) {
    int i = blockIdx.x * blockDim.x + threadIdx.x;
    if (i >= n64) return;
    int mode = *dmode;
    hp[i] = mode ? ((const u16*)pos)[i] : f2bf(((const float*)pos)[i]);
}

// ---------------- hp (bf16) -> f32 ----------------
__global__ void k_cvt(const u16* __restrict__ in, float* __restrict__ out, int n) {
    int i = blockIdx.x * blockDim.x + threadIdx.x;
    if (i < n) out[i] = bf2f(in[i]);
}

// ---------------- weight pre-split: W -> packed {hi,lo} bf16, replicated NCPY times
// Replication spreads the B-read hotspot: ~780 resident GEMM blocks otherwise all
// hammer the same ~128 L2 lines per K-panel in lock-step.
struct PWArgs {
    const void* src[8];
    u16* dst[8];
    int K[8];
    int BM[8];
    int cstride;   // u16 elements per copy
};

__global__ void k_prepw(PWArgs a, const int* __restrict__ dmode) {
    int mode = *dmode;
    int g = blockIdx.x * blockDim.x + threadIdx.x;
    int stride = gridDim.x * blockDim.x;
    for (int m = 0; m < 8; m++) {
        int bm = a.BM[m];
        int bmsh = (bm == 128) ? 7 : 6;
        int n = a.K[m] * bm;
        u16* d = a.dst[m];
        const void* s = a.src[m];
        for (int i = g; i < n; i += stride) {
            int k = i >> bmsh, c = i & (bm - 1);
            float v = mode ? bf2f(((const u16*)s)[i]) : ((const float*)s)[i];
            u16 hi = f2bf(v);
            u16 lo = f2bf(v - bf2f(hi));
            size_t o = ((size_t)((k >> 5) * 2) * bm + c) * 32 + (k & 31);
            for (int cc = 0; cc < NCPY; cc++) {
                d[o + (size_t)cc * a.cstride] = hi;
                d[o + (size_t)bm * 32 + (size_t)cc * a.cstride] = lo;
            }
        }
    }
}

// ---------------- MFMA GEMM + fused el/er epilogue ----------------
// Round-8 structure (best measured): LDS-free, 64-row blocks, runtime-K loop.
// New: per-block B copy select (hotspot spread) + kt start rotation (desync).
template <int BM, bool HASB2, bool C1H>
__launch_bounds__(256, 4)
__global__ void k_gemm(const void* A1, const u16* __restrict__ A2,
                       const u16* __restrict__ B1p, const u16* __restrict__ B2p,
                       void* __restrict__ C1, u16* C2, float* __restrict__ att,
                       const void* __restrict__ al, const void* __restrict__ ar,
                       int N, int K, int s1, const int* __restrict__ dmode,
                       int a1_input, int cstride) {
    constexpr int NR = BM / 32;            // 16-col frag tiles per wave (4 or 2)
    constexpr int NMAT = HASB2 ? 2 : 1;

    const int mode = *dmode;
    const int a1f32 = (a1_input && mode == 0) ? 1 : 0;
    const int bsplit = (mode == 0) ? 1 : 0;

    const int tid = threadIdx.x;
    const int lane = tid & 63;
    const int wid = tid >> 6;
    const int l15 = lane & 15, l4 = lane >> 4;
    const int r0 = blockIdx.x * 64;
    const int wrow0 = (wid >> 1) * 32;
    const int wcol0 = (wid & 1) * (BM / 2);
    const int ko = l4 * 8;                 // k offset of my 8-elem fragment

    // B copy select: neighbor blocks (>>2) share a copy for L1 reuse.
    const size_t coff = (size_t)((blockIdx.x >> 2) & (NCPY - 1)) * (size_t)cstride;
    const u16* b1 = B1p + coff;
    const u16* b2 = HASB2 ? (B2p + coff) : nullptr;

    int frow[2];
#pragma unroll
    for (int m = 0; m < 2; m++) {
        int r = r0 + wrow0 + m * 16 + l15;
        frow[m] = r < N ? r : N - 1;
    }

    f32x4 acc[NMAT][2][NR];
    const f32x4 fz = {0.f, 0.f, 0.f, 0.f};
#pragma unroll
    for (int m2 = 0; m2 < NMAT; m2++)
#pragma unroll
        for (int m = 0; m < 2; m++)
#pragma unroll
            for (int n = 0; n < NR; n++) acc[m2][m][n] = fz;

    const int NKT = K >> 5;
    const int rot = (int)((u32)(blockIdx.x >> 2) % (u32)NKT);
    for (int tt = 0; tt < NKT; tt++) {
        int kt = tt + rot;
        if (kt >= NKT) kt -= NKT;
        const int k0 = kt << 5;
        const int doAlo = (a1f32 && k0 < 128) ? 1 : 0;

        uint4 ah[2], alo[2];
#pragma unroll
        for (int m = 0; m < 2; m++) {
            if (k0 >= 128) {               // A2 region (always bf16, stride 64)
                ah[m] = *(const uint4*)(A2 + (size_t)frow[m] * 64 + (k0 - 128) + ko);
            } else if (!a1f32) {           // A1 bf16
                ah[m] = *(const uint4*)((const u16*)A1 + (size_t)frow[m] * s1 + k0 + ko);
            } else {                       // A1 f32: load 32B, split hi/lo in regs
                const float* p = (const float*)A1 + (size_t)frow[m] * s1 + k0 + ko;
                union { uint4 u[2]; float f[8]; } fa;
                fa.u[0] = *(const uint4*)p;
                fa.u[1] = *(const uint4*)(p + 4);
                u16 hi[8], lo[8];
#pragma unroll
                for (int i = 0; i < 8; i++) {
                    hi[i] = f2bf(fa.f[i]);
                    lo[i] = f2bf(fa.f[i] - bf2f(hi[i]));   // exact residual (Sterbenz)
                }
                ah[m] = packu4(hi);
                alo[m] = packu4(lo);
            }
        }

        const size_t bbase = ((size_t)kt * 2) * BM * 32 + (size_t)l4 * 8;
#pragma unroll
        for (int n = 0; n < NR; n++) {
            const int c = wcol0 + n * 16 + l15;
            const size_t co = (size_t)c * 32;
#pragma unroll
            for (int m2 = 0; m2 < NMAT; m2++) {
                const u16* bp = (m2 == 0 ? b1 : b2) + bbase + co;
                uint4 bh = *(const uint4*)bp;
#pragma unroll
                for (int m = 0; m < 2; m++)
                    acc[m2][m][n] = mfma16(ah[m], bh, acc[m2][m][n]);
                if (bsplit) {
                    uint4 bl = *(const uint4*)(bp + (size_t)BM * 32);
#pragma unroll
                    for (int m = 0; m < 2; m++)
                        acc[m2][m][n] = mfma16(ah[m], bl, acc[m2][m][n]);
                }
                if (doAlo) {
#pragma unroll
                    for (int m = 0; m < 2; m++)
                        acc[m2][m][n] = mfma16(alo[m], bh, acc[m2][m][n]);
                }
            }
        }
    }

    __syncthreads();   // in-place safety: all block A-reads done before C2 writes

    // ---- epilogue: C stores + fused el/er ----
    float alc[NR], arc[NR];
#pragma unroll
    for (int n = 0; n < NR; n++) {
        int c = wcol0 + n * 16 + l15;
        alc[n] = ldf(al, c, mode);
        arc[n] = ldf(ar, c, mode);
    }
    const int hc = wid & 1;
#pragma unroll
    for (int m = 0; m < 2; m++) {
#pragma unroll
        for (int r = 0; r < 4; r++) {
            const int gr = r0 + wrow0 + m * 16 + l4 * 4 + r;
            float el = 0.f, er = 0.f;
#pragma unroll
            for (int n = 0; n < NR; n++) {
                float v = acc[0][m][n][r];
                el = fmaf(v, alc[n], el);
                er = fmaf(v, arc[n], er);
            }
#pragma unroll
            for (int o = 1; o <= 8; o <<= 1) {   // reduce the 16 col-lanes (same row)
                el += __shfl_xor(el, o, 64);
                er += __shfl_xor(er, o, 64);
            }
            if (gr < N) {
#pragma unroll
                for (int n = 0; n < NR; n++) {
                    const int c = wcol0 + n * 16 + l15;
                    float v = acc[0][m][n][r];
                    if constexpr (C1H)
                        ((u16*)C1)[(size_t)gr * BM + c] = f2h(v);
                    else
                        ((float*)C1)[(size_t)gr * BM + c] = v;
                    if constexpr (HASB2)
                        C2[(size_t)gr * 128 + c] = f2bf(acc[1][m][n][r]);
                }
                if (l15 == 0) {
                    att[(size_t)gr * 4 + hc] = el;
                    att[(size_t)gr * 4 + 2 + hc] = er;
                }
            }
        }
    }
}

// ---------------- edge aggregation ----------------
// gat layers 0/1: fp16 H, wave per node, lane owns feature elems {2l, 2l+1}
// (head = l>>5). Gather unroll-8: 8 independent row loads in flight per wave.
__global__ void k_edge_gat2(const int* __restrict__ off, const int* __restrict__ ssrc,
                            const u16* __restrict__ h, const float* __restrict__ att,
                            const u16* __restrict__ res, u16* __restrict__ outf, int N) {
    __shared__ float pbuf[4][2][64];
    __shared__ int sbuf[4][64];
    int wv = threadIdx.x >> 6;
    int node = blockIdx.x * 4 + wv;
    int lane = threadIdx.x & 63;
    if (node >= N) return;
    const int hd = lane >> 5;            // head of my elems (2*lane)>>6
    int beg = off[node], end = off[node + 1];
    float4 a4 = *(const float4*)&att[(size_t)node * 4];
    float er0 = a4.z, er1 = a4.w;
    float m0 = -1e30f, m1 = -1e30f, d0 = 0.f, d1 = 0.f, O0 = 0.f, O1 = 0.f;
    for (int c = beg; c < end; c += 64) {
        int cn = min(end - c, 64);
        int s = 0;
        float x0 = -1e30f, x1 = -1e30f;
        if (lane < cn) {
            s = ssrc[c + lane];
            float2 e = *(const float2*)&att[(size_t)s * 4];
            x0 = lrelu(e.x + er0);
            x1 = lrelu(e.y + er1);
        }
        float cm0 = x0, cm1 = x1;
#pragma unroll
        for (int o = 32; o; o >>= 1) {
            cm0 = fmaxf(cm0, __shfl_xor(cm0, o, 64));
            cm1 = fmaxf(cm1, __shfl_xor(cm1, o, 64));
        }
        float nm0 = fmaxf(m0, cm0), nm1 = fmaxf(m1, cm1);
        float p0 = (lane < cn) ? __expf(x0 - nm0) : 0.f;
        float p1 = (lane < cn) ? __expf(x1 - nm1) : 0.f;
        float cd0 = p0, cd1 = p1;
#pragma unroll
        for (int o = 32; o; o >>= 1) {
            cd0 += __shfl_xor(cd0, o, 64);
            cd1 += __shfl_xor(cd1, o, 64);
        }
        float sc0 = __expf(m0 - nm0), sc1 = __expf(m1 - nm1);
        d0 = d0 * sc0 + cd0; d1 = d1 * sc1 + cd1;
        float sch = hd ? sc1 : sc0;
        O0 *= sch; O1 *= sch;
        m0 = nm0; m1 = nm1;
        pbuf[wv][0][lane] = p0;
        pbuf[wv][1][lane] = p1;
        sbuf[wv][lane] = s;
        const float* pb = pbuf[wv][hd];
        int j = 0;
        for (; j + 7 < cn; j += 8) {     // 8 loads in flight
            u32 w[8];
#pragma unroll
            for (int t = 0; t < 8; t++)
                w[t] = *(const u32*)&h[(size_t)sbuf[wv][j + t] * 128 + 2 * lane];
#pragma unroll
            for (int t = 0; t < 8; t++) {
                float q = pb[j + t];
                O0 += q * h2f((u16)w[t]);
                O1 += q * h2f((u16)(w[t] >> 16));
            }
        }
        if (j + 3 < cn) {
            u32 w[4];
#pragma unroll
            for (int t = 0; t < 4; t++)
                w[t] = *(const u32*)&h[(size_t)sbuf[wv][j + t] * 128 + 2 * lane];
#pragma unroll
            for (int t = 0; t < 4; t++) {
                float q = pb[j + t];
                O0 += q * h2f((u16)w[t]);
                O1 += q * h2f((u16)(w[t] >> 16));
            }
            j += 4;
        }
        for (; j < cn; j++) {
            u32 w = *(const u32*)&h[(size_t)sbuf[wv][j] * 128 + 2 * lane];
            float q = pb[j];
            O0 += q * h2f((u16)w);
            O1 += q * h2f((u16)(w >> 16));
        }
    }
    float dd = hd ? d1 : d0;
    float o0 = (end > beg) ? O0 / dd : 0.f;
    float o1 = (end > beg) ? O1 / dd : 0.f;
    u32 rv = *(const u32*)&res[(size_t)node * 128 + 2 * lane];
    float a0 = o0 + bf2f((u16)rv);
    float a1 = o1 + bf2f((u16)(rv >> 16));
    a0 = a0 > 0.f ? a0 : (__expf(a0) - 1.f);  // elu
    a1 = a1 > 0.f ? a1 : (__expf(a1) - 1.f);
    *(u32*)&outf[(size_t)node * 128 + 2 * lane] = pack2(a0, a1);
}

// Final layer (mean over heads): fp16 H, edge-parity split, gather unroll-8.
__global__ void k_edge_gat_f(const int* __restrict__ off, const int* __restrict__ ssrc,
                             const u16* __restrict__ h, const float* __restrict__ att,
                             const u16* __restrict__ res, float* __restrict__ outs, int N) {
    __shared__ float pbuf[4][2][64];
    __shared__ int sbuf[4][64];
    int wv = threadIdx.x >> 6;
    int node = blockIdx.x * 4 + wv;
    int lane = threadIdx.x & 63;
    if (node >= N) return;
    const int par = lane >> 5;
    const int i = lane & 31;
    const int hd = i >> 4;               // head of elems 4i..4i+3
    int beg = off[node], end = off[node + 1];
    float4 a4 = *(const float4*)&att[(size_t)node * 4];
    float er0 = a4.z, er1 = a4.w;
    float m0 = -1e30f, m1 = -1e30f, d0 = 0.f, d1 = 0.f;
    float O[4] = {0.f, 0.f, 0.f, 0.f};
    for (int c = beg; c < end; c += 64) {
        int cn = min(end - c, 64);
        int s = 0;
        float x0 = -1e30f, x1 = -1e30f;
        if (lane < cn) {
            s = ssrc[c + lane];
            float2 e = *(const float2*)&att[(size_t)s * 4];
            x0 = lrelu(e.x + er0);
            x1 = lrelu(e.y + er1);
        }
        float cm0 = x0, cm1 = x1;
#pragma unroll
        for (int o = 32; o; o >>= 1) {
            cm0 = fmaxf(cm0, __shfl_xor(cm0, o, 64));
            cm1 = fmaxf(cm1, __shfl_xor(cm1, o, 64));
        }
        float nm0 = fmaxf(m0, cm0), nm1 = fmaxf(m1, cm1);
        float p0 = (lane < cn) ? __expf(x0 - nm0) : 0.f;
        float p1 = (lane < cn) ? __expf(x1 - nm1) : 0.f;
        float cd0 = p0, cd1 = p1;
#pragma unroll
        for (int o = 32; o; o >>= 1) {
            cd0 += __shfl_xor(cd0, o, 64);
            cd1 += __shfl_xor(cd1, o, 64);
        }
        float sc0 = __expf(m0 - nm0), sc1 = __expf(m1 - nm1);
        d0 = d0 * sc0 + cd0; d1 = d1 * sc1 + cd1;
        float sch = hd ? sc1 : sc0;
#pragma unroll
        for (int k = 0; k < 4; k++) O[k] *= sch;
        m0 = nm0; m1 = nm1;
        pbuf[wv][0][lane] = p0;
        pbuf[wv][1][lane] = p1;
        sbuf[wv][lane] = s;
        const float* pb = pbuf[wv][hd];
        int j = par;
        for (; j + 14 < cn; j += 16) {   // 8 edges of my parity, 8 loads in flight
            uint2 w[8];
#pragma unroll
            for (int t = 0; t < 8; t++)
                w[t] = *(const uint2*)&h[(size_t)sbuf[wv][j + 2 * t] * 128 + 4 * i];
#pragma unroll
            for (int t = 0; t < 8; t++) {
                float q = pb[j + 2 * t];
                O[0] += q * h2f((u16)w[t].x);
                O[1] += q * h2f((u16)(w[t].x >> 16));
                O[2] += q * h2f((u16)w[t].y);
                O[3] += q * h2f((u16)(w[t].y >> 16));
            }
        }
        if (j + 6 < cn) {                // 4 edges of my parity
            uint2 w[4];
#pragma unroll
            for (int t = 0; t < 4; t++)
                w[t] = *(const uint2*)&h[(size_t)sbuf[wv][j + 2 * t] * 128 + 4 * i];
#pragma unroll
            for (int t = 0; t < 4; t++) {
                float q = pb[j + 2 * t];
                O[0] += q * h2f((u16)w[t].x);
                O[1] += q * h2f((u16)(w[t].x >> 16));
                O[2] += q * h2f((u16)w[t].y);
                O[3] += q * h2f((u16)(w[t].y >> 16));
            }
            j += 8;
        }
        for (; j < cn; j += 2) {
            uint2 w = *(const uint2*)&h[(size_t)sbuf[wv][j] * 128 + 4 * i];
            float q = pb[j];
            O[0] += q * h2f((u16)w.x);
            O[1] += q * h2f((u16)(w.x >> 16));
            O[2] += q * h2f((u16)w.y);
            O[3] += q * h2f((u16)(w.y >> 16));
        }
    }
#pragma unroll
    for (int k = 0; k < 4; k++) O[k] += __shfl_xor(O[k], 32, 64);  // combine parities
    float dd = hd ? d1 : d0;
    uint2 rv = *(const uint2*)&res[(size_t)node * 128 + 4 * i];
    float a[4];
    a[0] = bf2f((u16)rv.x);
    a[1] = bf2f((u16)(rv.x >> 16));
    a[2] = bf2f((u16)rv.y);
    a[3] = bf2f((u16)(rv.y >> 16));
#pragma unroll
    for (int k = 0; k < 4; k++) {
        float o = (end > beg) ? O[k] / dd : 0.f;
        float v = o + a[k];
        a[k] = v > 0.f ? v : (__expf(v) - 1.f);  // elu
    }
    float b[4];
#pragma unroll
    for (int k = 0; k < 4; k++) b[k] = __shfl_xor(a[k], 16, 64);  // partner head
    if (lane < 16)
        *(float4*)&outs[(size_t)node * 64 + 4 * i] =
            make_float4(0.5f * (a[0] + b[0]), 0.5f * (a[1] + b[1]),
                        0.5f * (a[2] + b[2]), 0.5f * (a[3] + b[3]));
}

// pg: fp16 H [N,64], wave per node; edge-parity split, gather unroll-8.
__global__ void k_edge_pg2(const int* __restrict__ off, const int* __restrict__ ssrc,
                           const u16* __restrict__ h, const float* __restrict__ att,
                           u16* __restrict__ hp, int N) {
    __shared__ float pbuf[4][2][64];
    __shared__ int sbuf[4][64];
    int wv = threadIdx.x >> 6;
    int node = blockIdx.x * 4 + wv;
    int lane = threadIdx.x & 63;
    if (node >= N) return;
    const int par = lane >> 5;
    const int i = lane & 31;
    const int hd = i >> 4;               // head of elems 2i,2i+1
    int beg = off[node], end = off[node + 1];
    float4 a4 = *(const float4*)&att[(size_t)node * 4];
    float er0 = a4.z, er1 = a4.w;
    float m0 = -1e30f, m1 = -1e30f, d0 = 0.f, d1 = 0.f, O0 = 0.f, O1 = 0.f;
    for (int c = beg; c < end; c += 64) {
        int cn = min(end - c, 64);
        int s = 0;
        float x0 = -1e30f, x1 = -1e30f;
        if (lane < cn) {
            s = ssrc[c + lane];
            float2 e = *(const float2*)&att[(size_t)s * 4];
            x0 = lrelu(e.x + er0);
            x1 = lrelu(e.y + er1);
        }
        float cm0 = x0, cm1 = x1;
#pragma unroll
        for (int o = 32; o; o >>= 1) {
            cm0 = fmaxf(cm0, __shfl_xor(cm0, o, 64));
            cm1 = fmaxf(cm1, __shfl_xor(cm1, o, 64));
        }
        float nm0 = fmaxf(m0, cm0), nm1 = fmaxf(m1, cm1);
        float p0 = (lane < cn) ? __expf(x0 - nm0) : 0.f;
        float p1 = (lane < cn) ? __expf(x1 - nm1) : 0.f;
        float cd0 = p0, cd1 = p1;
#pragma unroll
        for (int o = 32; o; o >>= 1) {
            cd0 += __shfl_xor(cd0, o, 64);
            cd1 += __shfl_xor(cd1, o, 64);
        }
        float sc0 = __expf(m0 - nm0), sc1 = __expf(m1 - nm1);
        d0 = d0 * sc0 + cd0; d1 = d1 * sc1 + cd1;
        float sch = hd ? sc1 : sc0;
        O0 *= sch; O1 *= sch;
        m0 = nm0; m1 = nm1;
        pbuf[wv][0][lane] = p0;
        pbuf[wv][1][lane] = p1;
        sbuf[wv][lane] = s;
        const float* pb = pbuf[wv][hd];
        int j = par;
        for (; j + 14 < cn; j += 16) {   // 8 edges of my parity, 8 loads in flight
            u32 w[8];
#pragma unroll
            for (int t = 0; t < 8; t++)
                w[t] = *(const u32*)&h[(size_t)sbuf[wv][j + 2 * t] * 64 + 2 * i];
#pragma unroll
            for (int t = 0; t < 8; t++) {
                float q = pb[j + 2 * t];
                O0 += q * h2f((u16)w[t]);
                O1 += q * h2f((u16)(w[t] >> 16));
            }
        }
        if (j + 6 < cn) {                // 4 edges of my parity
            u32 w[4];
#pragma unroll
            for (int t = 0; t < 4; t++)
                w[t] = *(const u32*)&h[(size_t)sbuf[wv][j + 2 * t] * 64 + 2 * i];
#pragma unroll
            for (int t = 0; t < 4; t++) {
                float q = pb[j + 2 * t];
                O0 += q * h2f((u16)w[t]);
                O1 += q * h2f((u16)(w[t] >> 16));
            }
            j += 8;
        }
        for (; j < cn; j += 2) {
            u32 w = *(const u32*)&h[(size_t)sbuf[wv][j] * 64 + 2 * i];
            float q = pb[j];
            O0 += q * h2f((u16)w);
            O1 += q * h2f((u16)(w >> 16));
        }
    }
    O0 += __shfl_xor(O0, 32, 64);        // combine edge parities
    O1 += __shfl_xor(O1, 32, 64);
    if (lane < 32) {
        float dd = hd ? d1 : d0;
        float o0 = (end > beg) ? O0 / dd : 0.f;
        float o1 = (end > beg) ? O1 / dd : 0.f;
        u32 rv = *(const u32*)&hp[(size_t)node * 64 + 2 * i];
        float a0 = tanhf(o0 + bf2f((u16)rv));
        float a1 = tanhf(o1 + bf2f((u16)(rv >> 16)));
        *(u32*)&hp[(size_t)node * 64 + 2 * i] = pack2(a0, a1);
    }
}

// ---------------- launch ----------------
extern "C" void kernel_launch(void* const* d_in, const int* in_sizes, int n_in,
                              void* d_out, int out_size, void* d_ws, size_t ws_size,
                              hipStream_t stream) {
    const int N = NN, E = NE;
    const void* fvs = d_in[0];
    const void* pos = d_in[1];
    const int* src = (const int*)d_in[2];
    const int* dst = (const int*)d_in[3];
    const void* gW[3]  = {d_in[4],  d_in[8],  d_in[12]};
    const void* gal[3] = {d_in[5],  d_in[9],  d_in[13]};
    const void* gar[3] = {d_in[6],  d_in[10], d_in[14]};
    const void* grW[3] = {d_in[7],  d_in[11], d_in[15]};
    const void* pW[2]  = {d_in[16], d_in[19]};
    const void* pal[2] = {d_in[17], d_in[20]};
    const void* par[2] = {d_in[18], d_in[21]};

    // packed weight geometry (u16 counts)
    const size_t GSZ = (size_t)192 * 128 * 2;   // u16 per gat matrix (hi+lo)
    const size_t PSZ = (size_t)64 * 64 * 2;
    const size_t CS  = 6 * GSZ + 2 * PSZ;       // u16 per copy

    // ---- workspace layout (wrap-safe) ----
    auto al256 = [](size_t b) { return (b + 255) & ~(size_t)255; };
    size_t sz_dmode = al256(4);
    size_t sz_bsum  = al256(32 * 4);
    size_t sz_bcur  = al256(256 * 4);
    size_t sz_att   = al256((size_t)N * 4 * 4);   // also hosts cnt during CSR build
    size_t sz_off   = al256((size_t)(N + 1) * 4);
    size_t sz_ssrc  = al256((size_t)E * 4);
    size_t sz_hs    = al256((size_t)N * 128 * 2);
    size_t sz_hp    = al256((size_t)N * 64 * 2);
    size_t sz_wpk   = al256(CS * NCPY * 2);       // NCPY replicated copies
    size_t need = sz_dmode + sz_bsum + sz_bcur + sz_att + sz_off + sz_ssrc
                + sz_hs + sz_hp + sz_wpk;
    int bad = (need > ws_size) ? 1 : 0;

    size_t cur = 0;
    auto alloc = [&](size_t bytes) {
        if (cur + bytes > ws_size) cur = 0;
        char* p = (char*)d_ws + cur;
        if (bytes <= ws_size) cur += bytes;
        return p;
    };
    int* dmode  = (int*)alloc(sz_dmode);
    int* bsum   = (int*)alloc(sz_bsum);
    int* bcur   = (int*)alloc(sz_bcur);
    float* att  = (float*)alloc(sz_att);
    int* off    = (int*)alloc(sz_off);
    int* ssrc   = (int*)alloc(sz_ssrc);
    u16* hs     = (u16*)alloc(sz_hs);
    u16* hp     = (u16*)alloc(sz_hp);
    u16* wpk    = (u16*)alloc(sz_wpk);

    // packed weight slots within copy 0: [gW0, grW0, gW1, grW1, gW2, grW2, pW0, pW1]
    u16* Bp[8];
    for (int m = 0; m < 6; m++) Bp[m] = wpk + (size_t)m * GSZ;
    Bp[6] = wpk + 6 * GSZ;
    Bp[7] = Bp[6] + PSZ;

    // cnt aliases att; tmp (binned edges, 3.2MB) aliases hs (dead before first GEMM).
    int* cnt = (int*)att;
    u32* tmp = (u32*)hs;

    void* H = d_out;   // transformed features in d_out: fp16 [N,128]; dead at end

    hipMemsetAsync(cnt, 0, (size_t)N * 4, stream);

    k_detect<<<1, 256, 0, stream>>>((const u16*)fvs, dmode);

    PWArgs pwa;
    pwa.src[0] = gW[0]; pwa.src[1] = grW[0];
    pwa.src[2] = gW[1]; pwa.src[3] = grW[1];
    pwa.src[4] = gW[2]; pwa.src[5] = grW[2];
    pwa.src[6] = pW[0]; pwa.src[7] = pW[1];
    for (int m = 0; m < 8; m++) {
        pwa.dst[m] = Bp[m];
        pwa.K[m] = (m < 6) ? 192 : 64;
        pwa.BM[m] = (m < 6) ? 128 : 64;
    }
    pwa.cstride = (int)CS;
    k_prepw<<<64, 256, 0, stream>>>(pwa, dmode);

    int eb = (E + 255) / 256;
    int nbS = (N + 2047) / 2048;
    int nbk = (N + BKT - 1) / BKT;
    k_hist<<<eb, 256, 0, stream>>>(dst, cnt, E);
    k_scan1<<<nbS, 256, 0, stream>>>(cnt, off, bsum, N);
    k_scan2<<<nbS, 256, 0, stream>>>(bsum, off, N, nbS);
    k_binit<<<1, 256, 0, stream>>>(off, bcur, nbk);
    k_fillA<<<(E + FBLK - 1) / FBLK, 256, 0, stream>>>(src, dst, bcur, tmp, E);
    k_fillB<<<nbk, 256, 0, stream>>>(off, tmp, ssrc, N);

    k_init<<<(N * 64 + 255) / 256, 256, 0, stream>>>(pos, hp, dmode, N * 64);

    int gb = (N + 63) / 64;
    int nb = (N + 3) / 4;
    int cs = (int)CS;

    // ---- layer 0 ----
    k_gemm<128, true, true><<<gb, 256, 0, stream>>>(fvs, hp, Bp[0], Bp[1], H, hs, att, gal[0], gar[0], N, 192, 128, dmode, 1, cs);
    k_edge_gat2<<<nb, 256, 0, stream>>>(off, ssrc, (u16*)H, att, hs, hs, N);
    k_gemm<64, false, true><<<gb, 256, 0, stream>>>(hp, nullptr, Bp[6], nullptr, H, nullptr, att, pal[0], par[0], N, 64, 64, dmode, 0, cs);
    k_edge_pg2<<<nb, 256, 0, stream>>>(off, ssrc, (u16*)H, att, hp, N);

    // ---- layer 1 ----
    k_gemm<128, true, true><<<gb, 256, 0, stream>>>(hs, hp, Bp[2], Bp[3], H, hs, att, gal[1], gar[1], N, 192, 128, dmode, 0, cs);
    k_edge_gat2<<<nb, 256, 0, stream>>>(off, ssrc, (u16*)H, att, hs, hs, N);
    k_gemm<64, false, true><<<gb, 256, 0, stream>>>(hp, nullptr, Bp[7], nullptr, H, nullptr, att, pal[1], par[1], N, 64, 64, dmode, 0, cs);
    k_edge_pg2<<<nb, 256, 0, stream>>>(off, ssrc, (u16*)H, att, hp, N);  // hp = pg1 out (tanh)

    // ---- output layer (fp16 H) ----
    k_gemm<128, true, true><<<gb, 256, 0, stream>>>(hs, hp, Bp[4], Bp[5], H, hs, att, gal[2], gar[2], N, 192, 128, dmode, 0, cs);
    // final mean written in-place into hs rows as f32 (row = 256B = 64 floats)
    k_edge_gat_f<<<nb, 256, 0, stream>>>(off, ssrc, (u16*)H, att, hs, (float*)hs, N);

    // H (= d_out) now dead; materialize outputs as f32.
    hipMemcpyAsync((float*)d_out, (float*)hs, (size_t)N * 64 * 4, hipMemcpyDeviceToDevice, stream);
    k_cvt<<<(N * 64 + 255) / 256, 256, 0, stream>>>(hp, (float*)d_out + (size_t)N * 64, N * 64);

    // Diagnostic: if workspace too small, out[0] reads ~100000 + MB*1000.
    if (bad) {
        float v = 100000.f + 1000.f * (float)(ws_size >> 20);
        k_tracer<<<1, 64, 0, stream>>>((float*)d_out, v);
    }
}

// Round 16
// 563.667 us; speedup vs baseline: 1.0328x; 1.0328x over previous
//
#include <hip/hip_runtime.h>

#define NN 50000
#define NE 800000
#define FBLK 8192
#define BKT 256
#define NCPY 8

typedef unsigned short u16;
typedef unsigned int u32;

typedef float f32x4 __attribute__((ext_vector_type(4)));
typedef __bf16 bf16x8 __attribute__((ext_vector_type(8)));
static_assert(sizeof(bf16x8) == 16, "bf16x8 must be 16B");

__device__ __forceinline__ float bf2f(u16 u) {
    u32 x = ((u32)u) << 16;
    return __uint_as_float(x);
}
__device__ __forceinline__ u16 f2bf(float f) {
    u32 x = __float_as_uint(f);
    u32 r = (x + 0x7fffu + ((x >> 16) & 1u)) >> 16;  // round-nearest-even
    return (u16)r;
}
__device__ __forceinline__ u32 pack2(float a, float b) {
    return (u32)f2bf(a) | ((u32)f2bf(b) << 16);
}
// fp16 (IEEE half) pack/unpack: H tensor is fp16 (2^-11 rel err vs bf16's 2^-8).
__device__ __forceinline__ u16 f2h(float f) {
    _Float16 h = (_Float16)f;
    union { _Float16 h; u16 u; } c; c.h = h;
    return c.u;
}
__device__ __forceinline__ float h2f(u16 u) {
    union { u16 u; _Float16 h; } c; c.u = u;
    return (float)c.h;
}
__device__ __forceinline__ uint4 packu4(const u16* h) {
    uint4 u;
    u.x = (u32)h[0] | ((u32)h[1] << 16);
    u.y = (u32)h[2] | ((u32)h[3] << 16);
    u.z = (u32)h[4] | ((u32)h[5] << 16);
    u.w = (u32)h[6] | ((u32)h[7] << 16);
    return u;
}
__device__ __forceinline__ float ldf(const void* p, size_t idx, int mode) {
    return mode ? bf2f(((const u16*)p)[idx]) : ((const float*)p)[idx];
}
__device__ __forceinline__ float lrelu(float x) { return x > 0.f ? x : 0.2f * x; }

// D = A.B + C ; A/B frags: 8 contiguous k per lane (k-group = lane>>4), lane&15 = row(A)/col(B)
// D: col = lane&15, row = (lane>>4)*4 + reg   [measured m89/m91]
__device__ __forceinline__ f32x4 mfma16(uint4 a, uint4 b, f32x4 c) {
    union { uint4 u; bf16x8 b; } ua, ub;
    ua.u = a; ub.u = b;
    return __builtin_amdgcn_mfma_f32_16x16x32_bf16(ua.b, ub.b, c, 0, 0, 0);
}

// ---------------- diagnostics ----------------
__global__ void k_tracer(float* out, float v) {
    if (threadIdx.x == 0 && blockIdx.x == 0) out[0] = v;
}

// ---------------- dtype detect (0 = f32 inputs, 1 = bf16 inputs) ----------------
__global__ void k_detect(const u16* __restrict__ fvs, int* __restrict__ mode) {
    __shared__ int cnt[256];
    int t = threadIdx.x;
    int bad = 0;
    for (int i = 0; i < 16; i++) {
        u16 u = fvs[(size_t)(t * 16 + i) * 2];
        int e = (u >> 7) & 0xff;
        if (e == 255 || e >= 134 || e <= 100) bad++;
    }
    cnt[t] = bad;
    __syncthreads();
    for (int d = 128; d; d >>= 1) {
        if (t < d) cnt[t] += cnt[t + d];
        __syncthreads();
    }
    if (t == 0) *mode = (cnt[0] > 2048) ? 0 : 1;
}

// ---------------- CSR build ----------------
__global__ void k_hist(const int* __restrict__ dst, int* __restrict__ cnt, int E) {
    int e = blockIdx.x * blockDim.x + threadIdx.x;
    if (e < E) atomicAdd(&cnt[dst[e]], 1);
}

// Multi-block scan, 2048 elems/block (8/thread via int4).
__global__ void k_scan1(const int* __restrict__ cnt, int* __restrict__ off,
                        int* __restrict__ bsum, int N) {
    __shared__ int wsum[4];
    int t = threadIdx.x;
    int base = blockIdx.x * 2048 + t * 8;
    int e[8];
    if (base + 8 <= N) {
        int4 v0 = *(const int4*)&cnt[base];
        int4 v1 = *(const int4*)&cnt[base + 4];
        e[0] = v0.x; e[1] = v0.y; e[2] = v0.z; e[3] = v0.w;
        e[4] = v1.x; e[5] = v1.y; e[6] = v1.z; e[7] = v1.w;
    } else {
#pragma unroll
        for (int i = 0; i < 8; i++) e[i] = (base + i < N) ? cnt[base + i] : 0;
    }
    int s = 0;
    int ps[8];
#pragma unroll
    for (int i = 0; i < 8; i++) { ps[i] = s; s += e[i]; }
    int lane = t & 63, wv = t >> 6;
    int sc = s;
#pragma unroll
    for (int o = 1; o < 64; o <<= 1) {
        int u = __shfl_up(sc, o, 64);
        if (lane >= o) sc += u;
    }
    if (lane == 63) wsum[wv] = sc;
    __syncthreads();
    int woff = 0;
    for (int w = 0; w < wv; w++) woff += wsum[w];
    int ex = woff + sc - s;   // exclusive prefix of this thread within block
#pragma unroll
    for (int i = 0; i < 8; i++) ps[i] += ex;
    if (base + 8 <= N) {
        *(int4*)&off[base] = make_int4(ps[0], ps[1], ps[2], ps[3]);
        *(int4*)&off[base + 4] = make_int4(ps[4], ps[5], ps[6], ps[7]);
    } else {
#pragma unroll
        for (int i = 0; i < 8; i++)
            if (base + i < N) off[base + i] = ps[i];
    }
    if (t == 255) bsum[blockIdx.x] = woff + sc;   // block total
}

__global__ void k_scan2(const int* __restrict__ bsum, int* __restrict__ off,
                        int N, int nb) {
    int b = blockIdx.x, t = threadIdx.x;
    int boff = 0;
    for (int i = 0; i < b; i++) boff += bsum[i];   // uniform, <=24 iters
    int base = b * 2048 + t * 8;
    if (b > 0) {
        if (base + 8 <= N) {
            int4 a = *(int4*)&off[base];
            int4 c = *(int4*)&off[base + 4];
            a.x += boff; a.y += boff; a.z += boff; a.w += boff;
            c.x += boff; c.y += boff; c.z += boff; c.w += boff;
            *(int4*)&off[base] = a;
            *(int4*)&off[base + 4] = c;
        } else {
#pragma unroll
            for (int i = 0; i < 8; i++)
                if (base + i < N) off[base + i] += boff;
        }
    }
    if (b == nb - 1 && t == 255) off[N] = boff + bsum[b];
}

// ---- CSR fill via two-pass LDS multisplit ----
__global__ void k_binit(const int* __restrict__ off, int* __restrict__ bcur, int nbk) {
    int b = threadIdx.x;
    if (b < nbk) bcur[b] = off[b * BKT];
    else if (b < 256) bcur[b] = 0;
}

__launch_bounds__(256)
__global__ void k_fillA(const int* __restrict__ src, const int* __restrict__ dst,
                        int* __restrict__ bcur, u32* __restrict__ tmp, int E) {
    __shared__ int hist[256];
    __shared__ int lbase[256];
    __shared__ int gbase[256];
    __shared__ int lcur[256];
    __shared__ u32 outrec[FBLK];
    __shared__ unsigned char bslot[FBLK];
    int t = threadIdx.x;
    int e0 = blockIdx.x * FBLK;
    int bn = min(E - e0, FBLK);
    hist[t] = 0;
    __syncthreads();
    for (int i = t; i < bn; i += 256)
        atomicAdd(&hist[dst[e0 + i] >> 8], 1);
    __syncthreads();
    if (t == 0) {
        int run = 0;
        for (int b = 0; b < 256; b++) { lbase[b] = run; run += hist[b]; }
    }
    __syncthreads();
    lcur[t] = lbase[t];
    gbase[t] = hist[t] ? atomicAdd(&bcur[t], hist[t]) : 0;
    __syncthreads();
    for (int i = t; i < bn; i += 256) {
        int d = dst[e0 + i];
        int s = src[e0 + i];
        int b = d >> 8;
        int slot = atomicAdd(&lcur[b], 1);
        outrec[slot] = (u32)s | ((u32)(d & 255) << 24);   // src < 2^24
        bslot[slot] = (unsigned char)b;
    }
    __syncthreads();
    for (int i = t; i < bn; i += 256) {
        int b = bslot[i];
        tmp[gbase[b] + (i - lbase[b])] = outrec[i];       // contiguous bucket runs
    }
}

__launch_bounds__(256)
__global__ void k_fillB(const int* __restrict__ off, const u32* __restrict__ tmp,
                        int* __restrict__ ssrc, int N) {
    __shared__ int lcur[BKT];
    __shared__ u32 outv[FBLK];
    int b = blockIdx.x, t = threadIdx.x;
    int n0 = b * BKT;
    int nn = min(N - n0, BKT);
    int nbeg = off[n0], nend = off[n0 + nn];
    int sz = nend - nbeg;
    for (int i = t; i < nn; i += 256) lcur[i] = off[n0 + i] - nbeg;
    __syncthreads();
    if (sz <= FBLK) {
        for (int i = t; i < sz; i += 256) {
            u32 r = tmp[nbeg + i];
            int slot = atomicAdd(&lcur[r >> 24], 1);
            outv[slot] = r & 0x00FFFFFFu;
        }
        __syncthreads();
        for (int i = t; i < sz; i += 256)
            ssrc[nbeg + i] = (int)outv[i];
    } else {  // bucket overflow fallback (correctness only)
        for (int i = t; i < sz; i += 256) {
            u32 r = tmp[nbeg + i];
            int slot = atomicAdd(&lcur[r >> 24], 1);
            ssrc[nbeg + slot] = (int)(r & 0x00FFFFFFu);
        }
    }
}

// ---------------- init: hp = bf16(pos) ----------------
__global__ void k_init(const void* __restrict__ pos, u16* __restrict__ hp,
                       const int* __restrict__ dmode, int n64) {
    int i = blockIdx.x * blockDim.x + threadIdx.x;
    if (i >= n64) return;
    int mode = *dmode;
    hp[i] = mode ? ((const u16*)pos)[i] : f2bf(((const float*)pos)[i]);
}

// ---------------- hp (bf16) -> f32 ----------------
__global__ void k_cvt(const u16* __restrict__ in, float* __restrict__ out, int n) {
    int i = blockIdx.x * blockDim.x + threadIdx.x;
    if (i < n) out[i] = bf2f(in[i]);
}

// ---------------- weight pre-split: W -> packed {hi,lo} bf16 (copy 0 only) ----------------
struct PWArgs {
    const void* src[8];
    u16* dst[8];
    int K[8];
    int BM[8];
};

__global__ void k_prepw(PWArgs a, const int* __restrict__ dmode) {
    int mode = *dmode;
    int g = blockIdx.x * blockDim.x + threadIdx.x;
    int stride = gridDim.x * blockDim.x;
    for (int m = 0; m < 8; m++) {
        int bm = a.BM[m];
        int bmsh = (bm == 128) ? 7 : 6;
        int n = a.K[m] * bm;
        u16* d = a.dst[m];
        const void* s = a.src[m];
        for (int i = g; i < n; i += stride) {
            int k = i >> bmsh, c = i & (bm - 1);
            float v = mode ? bf2f(((const u16*)s)[i]) : ((const float*)s)[i];
            u16 hi = f2bf(v);
            u16 lo = f2bf(v - bf2f(hi));
            size_t o = ((size_t)((k >> 5) * 2) * bm + c) * 32 + (k & 31);
            d[o] = hi;
            d[o + (size_t)bm * 32] = lo;
        }
    }
}

// Vectorized clone of packed-weight copy 0 into copies 1..NCPY-1 (uint4 = 16B units).
// Replication spreads the GEMM B-read hotspot across distinct L2 line sets
// (round-14: k_gemm 53 -> 46.5us); this kernel materializes it cheaply (~4.4MB coalesced).
__global__ void k_wcopy(u32* __restrict__ wpk, int nq, int cq) {
    // nq = uint4 count of one copy; cq = uint4 stride between copies
    int i = blockIdx.x * blockDim.x + threadIdx.x;
    if (i >= nq * (NCPY - 1)) return;
    int cc = i / nq + 1;
    int q = i - (cc - 1) * nq;
    uint4* p = (uint4*)wpk;
    p[(size_t)cc * cq + q] = p[q];
}

// ---------------- MFMA GEMM + fused el/er epilogue ----------------
// Round-8 structure + round-14 contention fixes (B copy select + kt rotation).
template <int BM, bool HASB2, bool C1H>
__launch_bounds__(256, 4)
__global__ void k_gemm(const void* A1, const u16* __restrict__ A2,
                       const u16* __restrict__ B1p, const u16* __restrict__ B2p,
                       void* __restrict__ C1, u16* C2, float* __restrict__ att,
                       const void* __restrict__ al, const void* __restrict__ ar,
                       int N, int K, int s1, const int* __restrict__ dmode,
                       int a1_input, int cstride) {
    constexpr int NR = BM / 32;            // 16-col frag tiles per wave (4 or 2)
    constexpr int NMAT = HASB2 ? 2 : 1;

    const int mode = *dmode;
    const int a1f32 = (a1_input && mode == 0) ? 1 : 0;
    const int bsplit = (mode == 0) ? 1 : 0;

    const int tid = threadIdx.x;
    const int lane = tid & 63;
    const int wid = tid >> 6;
    const int l15 = lane & 15, l4 = lane >> 4;
    const int r0 = blockIdx.x * 64;
    const int wrow0 = (wid >> 1) * 32;
    const int wcol0 = (wid & 1) * (BM / 2);
    const int ko = l4 * 8;                 // k offset of my 8-elem fragment

    // B copy select: neighbor blocks (>>2) share a copy for L1 reuse.
    const size_t coff = (size_t)((blockIdx.x >> 2) & (NCPY - 1)) * (size_t)cstride;
    const u16* b1 = B1p + coff;
    const u16* b2 = HASB2 ? (B2p + coff) : nullptr;

    int frow[2];
#pragma unroll
    for (int m = 0; m < 2; m++) {
        int r = r0 + wrow0 + m * 16 + l15;
        frow[m] = r < N ? r : N - 1;
    }

    f32x4 acc[NMAT][2][NR];
    const f32x4 fz = {0.f, 0.f, 0.f, 0.f};
#pragma unroll
    for (int m2 = 0; m2 < NMAT; m2++)
#pragma unroll
        for (int m = 0; m < 2; m++)
#pragma unroll
            for (int n = 0; n < NR; n++) acc[m2][m][n] = fz;

    const int NKT = K >> 5;
    const int rot = (int)((u32)(blockIdx.x >> 2) % (u32)NKT);
    for (int tt = 0; tt < NKT; tt++) {
        int kt = tt + rot;
        if (kt >= NKT) kt -= NKT;
        const int k0 = kt << 5;
        const int doAlo = (a1f32 && k0 < 128) ? 1 : 0;

        uint4 ah[2], alo[2];
#pragma unroll
        for (int m = 0; m < 2; m++) {
            if (k0 >= 128) {               // A2 region (always bf16, stride 64)
                ah[m] = *(const uint4*)(A2 + (size_t)frow[m] * 64 + (k0 - 128) + ko);
            } else if (!a1f32) {           // A1 bf16
                ah[m] = *(const uint4*)((const u16*)A1 + (size_t)frow[m] * s1 + k0 + ko);
            } else {                       // A1 f32: load 32B, split hi/lo in regs
                const float* p = (const float*)A1 + (size_t)frow[m] * s1 + k0 + ko;
                union { uint4 u[2]; float f[8]; } fa;
                fa.u[0] = *(const uint4*)p;
                fa.u[1] = *(const uint4*)(p + 4);
                u16 hi[8], lo[8];
#pragma unroll
                for (int i = 0; i < 8; i++) {
                    hi[i] = f2bf(fa.f[i]);
                    lo[i] = f2bf(fa.f[i] - bf2f(hi[i]));   // exact residual (Sterbenz)
                }
                ah[m] = packu4(hi);
                alo[m] = packu4(lo);
            }
        }

        const size_t bbase = ((size_t)kt * 2) * BM * 32 + (size_t)l4 * 8;
#pragma unroll
        for (int n = 0; n < NR; n++) {
            const int c = wcol0 + n * 16 + l15;
            const size_t co = (size_t)c * 32;
#pragma unroll
            for (int m2 = 0; m2 < NMAT; m2++) {
                const u16* bp = (m2 == 0 ? b1 : b2) + bbase + co;
                uint4 bh = *(const uint4*)bp;
#pragma unroll
                for (int m = 0; m < 2; m++)
                    acc[m2][m][n] = mfma16(ah[m], bh, acc[m2][m][n]);
                if (bsplit) {
                    uint4 bl = *(const uint4*)(bp + (size_t)BM * 32);
#pragma unroll
                    for (int m = 0; m < 2; m++)
                        acc[m2][m][n] = mfma16(ah[m], bl, acc[m2][m][n]);
                }
                if (doAlo) {
#pragma unroll
                    for (int m = 0; m < 2; m++)
                        acc[m2][m][n] = mfma16(alo[m], bh, acc[m2][m][n]);
                }
            }
        }
    }

    __syncthreads();   // in-place safety: all block A-reads done before C2 writes

    // ---- epilogue: C stores + fused el/er ----
    float alc[NR], arc[NR];
#pragma unroll
    for (int n = 0; n < NR; n++) {
        int c = wcol0 + n * 16 + l15;
        alc[n] = ldf(al, c, mode);
        arc[n] = ldf(ar, c, mode);
    }
    const int hc = wid & 1;
#pragma unroll
    for (int m = 0; m < 2; m++) {
#pragma unroll
        for (int r = 0; r < 4; r++) {
            const int gr = r0 + wrow0 + m * 16 + l4 * 4 + r;
            float el = 0.f, er = 0.f;
#pragma unroll
            for (int n = 0; n < NR; n++) {
                float v = acc[0][m][n][r];
                el = fmaf(v, alc[n], el);
                er = fmaf(v, arc[n], er);
            }
#pragma unroll
            for (int o = 1; o <= 8; o <<= 1) {   // reduce the 16 col-lanes (same row)
                el += __shfl_xor(el, o, 64);
                er += __shfl_xor(er, o, 64);
            }
            if (gr < N) {
#pragma unroll
                for (int n = 0; n < NR; n++) {
                    const int c = wcol0 + n * 16 + l15;
                    float v = acc[0][m][n][r];
                    if constexpr (C1H)
                        ((u16*)C1)[(size_t)gr * BM + c] = f2h(v);
                    else
                        ((float*)C1)[(size_t)gr * BM + c] = v;
                    if constexpr (HASB2)
                        C2[(size_t)gr * 128 + c] = f2bf(acc[1][m][n][r]);
                }
                if (l15 == 0) {
                    att[(size_t)gr * 4 + hc] = el;
                    att[(size_t)gr * 4 + 2 + hc] = er;
                }
            }
        }
    }
}

// ---------------- edge aggregation ----------------
// gat layers 0/1: fp16 H, wave per node, lane owns feature elems {2l, 2l+1}
// (head = l>>5). Gather unroll-8: 8 independent row loads in flight per wave.
__global__ void k_edge_gat2(const int* __restrict__ off, const int* __restrict__ ssrc,
                            const u16* __restrict__ h, const float* __restrict__ att,
                            const u16* __restrict__ res, u16* __restrict__ outf, int N) {
    __shared__ float pbuf[4][2][64];
    __shared__ int sbuf[4][64];
    int wv = threadIdx.x >> 6;
    int node = blockIdx.x * 4 + wv;
    int lane = threadIdx.x & 63;
    if (node >= N) return;
    const int hd = lane >> 5;            // head of my elems (2*lane)>>6
    int beg = off[node], end = off[node + 1];
    float4 a4 = *(const float4*)&att[(size_t)node * 4];
    float er0 = a4.z, er1 = a4.w;
    float m0 = -1e30f, m1 = -1e30f, d0 = 0.f, d1 = 0.f, O0 = 0.f, O1 = 0.f;
    for (int c = beg; c < end; c += 64) {
        int cn = min(end - c, 64);
        int s = 0;
        float x0 = -1e30f, x1 = -1e30f;
        if (lane < cn) {
            s = ssrc[c + lane];
            float2 e = *(const float2*)&att[(size_t)s * 4];
            x0 = lrelu(e.x + er0);
            x1 = lrelu(e.y + er1);
        }
        float cm0 = x0, cm1 = x1;
#pragma unroll
        for (int o = 32; o; o >>= 1) {
            cm0 = fmaxf(cm0, __shfl_xor(cm0, o, 64));
            cm1 = fmaxf(cm1, __shfl_xor(cm1, o, 64));
        }
        float nm0 = fmaxf(m0, cm0), nm1 = fmaxf(m1, cm1);
        float p0 = (lane < cn) ? __expf(x0 - nm0) : 0.f;
        float p1 = (lane < cn) ? __expf(x1 - nm1) : 0.f;
        float cd0 = p0, cd1 = p1;
#pragma unroll
        for (int o = 32; o; o >>= 1) {
            cd0 += __shfl_xor(cd0, o, 64);
            cd1 += __shfl_xor(cd1, o, 64);
        }
        float sc0 = __expf(m0 - nm0), sc1 = __expf(m1 - nm1);
        d0 = d0 * sc0 + cd0; d1 = d1 * sc1 + cd1;
        float sch = hd ? sc1 : sc0;
        O0 *= sch; O1 *= sch;
        m0 = nm0; m1 = nm1;
        pbuf[wv][0][lane] = p0;
        pbuf[wv][1][lane] = p1;
        sbuf[wv][lane] = s;
        const float* pb = pbuf[wv][hd];
        int j = 0;
        for (; j + 7 < cn; j += 8) {     // 8 loads in flight
            u32 w[8];
#pragma unroll
            for (int t = 0; t < 8; t++)
                w[t] = *(const u32*)&h[(size_t)sbuf[wv][j + t] * 128 + 2 * lane];
#pragma unroll
            for (int t = 0; t < 8; t++) {
                float q = pb[j + t];
                O0 += q * h2f((u16)w[t]);
                O1 += q * h2f((u16)(w[t] >> 16));
            }
        }
        if (j + 3 < cn) {
            u32 w[4];
#pragma unroll
            for (int t = 0; t < 4; t++)
                w[t] = *(const u32*)&h[(size_t)sbuf[wv][j + t] * 128 + 2 * lane];
#pragma unroll
            for (int t = 0; t < 4; t++) {
                float q = pb[j + t];
                O0 += q * h2f((u16)w[t]);
                O1 += q * h2f((u16)(w[t] >> 16));
            }
            j += 4;
        }
        for (; j < cn; j++) {
            u32 w = *(const u32*)&h[(size_t)sbuf[wv][j] * 128 + 2 * lane];
            float q = pb[j];
            O0 += q * h2f((u16)w);
            O1 += q * h2f((u16)(w >> 16));
        }
    }
    float dd = hd ? d1 : d0;
    float o0 = (end > beg) ? O0 / dd : 0.f;
    float o1 = (end > beg) ? O1 / dd : 0.f;
    u32 rv = *(const u32*)&res[(size_t)node * 128 + 2 * lane];
    float a0 = o0 + bf2f((u16)rv);
    float a1 = o1 + bf2f((u16)(rv >> 16));
    a0 = a0 > 0.f ? a0 : (__expf(a0) - 1.f);  // elu
    a1 = a1 > 0.f ? a1 : (__expf(a1) - 1.f);
    *(u32*)&outf[(size_t)node * 128 + 2 * lane] = pack2(a0, a1);
}

// Final layer (mean over heads): fp16 H, edge-parity split, gather unroll-8.
__global__ void k_edge_gat_f(const int* __restrict__ off, const int* __restrict__ ssrc,
                             const u16* __restrict__ h, const float* __restrict__ att,
                             const u16* __restrict__ res, float* __restrict__ outs, int N) {
    __shared__ float pbuf[4][2][64];
    __shared__ int sbuf[4][64];
    int wv = threadIdx.x >> 6;
    int node = blockIdx.x * 4 + wv;
    int lane = threadIdx.x & 63;
    if (node >= N) return;
    const int par = lane >> 5;
    const int i = lane & 31;
    const int hd = i >> 4;               // head of elems 4i..4i+3
    int beg = off[node], end = off[node + 1];
    float4 a4 = *(const float4*)&att[(size_t)node * 4];
    float er0 = a4.z, er1 = a4.w;
    float m0 = -1e30f, m1 = -1e30f, d0 = 0.f, d1 = 0.f;
    float O[4] = {0.f, 0.f, 0.f, 0.f};
    for (int c = beg; c < end; c += 64) {
        int cn = min(end - c, 64);
        int s = 0;
        float x0 = -1e30f, x1 = -1e30f;
        if (lane < cn) {
            s = ssrc[c + lane];
            float2 e = *(const float2*)&att[(size_t)s * 4];
            x0 = lrelu(e.x + er0);
            x1 = lrelu(e.y + er1);
        }
        float cm0 = x0, cm1 = x1;
#pragma unroll
        for (int o = 32; o; o >>= 1) {
            cm0 = fmaxf(cm0, __shfl_xor(cm0, o, 64));
            cm1 = fmaxf(cm1, __shfl_xor(cm1, o, 64));
        }
        float nm0 = fmaxf(m0, cm0), nm1 = fmaxf(m1, cm1);
        float p0 = (lane < cn) ? __expf(x0 - nm0) : 0.f;
        float p1 = (lane < cn) ? __expf(x1 - nm1) : 0.f;
        float cd0 = p0, cd1 = p1;
#pragma unroll
        for (int o = 32; o; o >>= 1) {
            cd0 += __shfl_xor(cd0, o, 64);
            cd1 += __shfl_xor(cd1, o, 64);
        }
        float sc0 = __expf(m0 - nm0), sc1 = __expf(m1 - nm1);
        d0 = d0 * sc0 + cd0; d1 = d1 * sc1 + cd1;
        float sch = hd ? sc1 : sc0;
#pragma unroll
        for (int k = 0; k < 4; k++) O[k] *= sch;
        m0 = nm0; m1 = nm1;
        pbuf[wv][0][lane] = p0;
        pbuf[wv][1][lane] = p1;
        sbuf[wv][lane] = s;
        const float* pb = pbuf[wv][hd];
        int j = par;
        for (; j + 14 < cn; j += 16) {   // 8 edges of my parity, 8 loads in flight
            uint2 w[8];
#pragma unroll
            for (int t = 0; t < 8; t++)
                w[t] = *(const uint2*)&h[(size_t)sbuf[wv][j + 2 * t] * 128 + 4 * i];
#pragma unroll
            for (int t = 0; t < 8; t++) {
                float q = pb[j + 2 * t];
                O[0] += q * h2f((u16)w[t].x);
                O[1] += q * h2f((u16)(w[t].x >> 16));
                O[2] += q * h2f((u16)w[t].y);
                O[3] += q * h2f((u16)(w[t].y >> 16));
            }
        }
        if (j + 6 < cn) {                // 4 edges of my parity
            uint2 w[4];
#pragma unroll
            for (int t = 0; t < 4; t++)
                w[t] = *(const uint2*)&h[(size_t)sbuf[wv][j + 2 * t] * 128 + 4 * i];
#pragma unroll
            for (int t = 0; t < 4; t++) {
                float q = pb[j + 2 * t];
                O[0] += q * h2f((u16)w[t].x);
                O[1] += q * h2f((u16)(w[t].x >> 16));
                O[2] += q * h2f((u16)w[t].y);
                O[3] += q * h2f((u16)(w[t].y >> 16));
            }
            j += 8;
        }
        for (; j < cn; j += 2) {
            uint2 w = *(const uint2*)&h[(size_t)sbuf[wv][j] * 128 + 4 * i];
            float q = pb[j];
            O[0] += q * h2f((u16)w.x);
            O[1] += q * h2f((u16)(w.x >> 16));
            O[2] += q * h2f((u16)w.y);
            O[3] += q * h2f((u16)(w.y >> 16));
        }
    }
#pragma unroll
    for (int k = 0; k < 4; k++) O[k] += __shfl_xor(O[k], 32, 64);  // combine parities
    float dd = hd ? d1 : d0;
    uint2 rv = *(const uint2*)&res[(size_t)node * 128 + 4 * i];
    float a[4];
    a[0] = bf2f((u16)rv.x);
    a[1] = bf2f((u16)(rv.x >> 16));
    a[2] = bf2f((u16)rv.y);
    a[3] = bf2f((u16)(rv.y >> 16));
#pragma unroll
    for (int k = 0; k < 4; k++) {
        float o = (end > beg) ? O[k] / dd : 0.f;
        float v = o + a[k];
        a[k] = v > 0.f ? v : (__expf(v) - 1.f);  // elu
    }
    float b[4];
#pragma unroll
    for (int k = 0; k < 4; k++) b[k] = __shfl_xor(a[k], 16, 64);  // partner head
    if (lane < 16)
        *(float4*)&outs[(size_t)node * 64 + 4 * i] =
            make_float4(0.5f * (a[0] + b[0]), 0.5f * (a[1] + b[1]),
                        0.5f * (a[2] + b[2]), 0.5f * (a[3] + b[3]));
}

// pg: fp16 H [N,64], wave per node; edge-parity split, gather unroll-8.
__global__ void k_edge_pg2(const int* __restrict__ off, const int* __restrict__ ssrc,
                           const u16* __restrict__ h, const float* __restrict__ att,
                           u16* __restrict__ hp, int N) {
    __shared__ float pbuf[4][2][64];
    __shared__ int sbuf[4][64];
    int wv = threadIdx.x >> 6;
    int node = blockIdx.x * 4 + wv;
    int lane = threadIdx.x & 63;
    if (node >= N) return;
    const int par = lane >> 5;
    const int i = lane & 31;
    const int hd = i >> 4;               // head of elems 2i,2i+1
    int beg = off[node], end = off[node + 1];
    float4 a4 = *(const float4*)&att[(size_t)node * 4];
    float er0 = a4.z, er1 = a4.w;
    float m0 = -1e30f, m1 = -1e30f, d0 = 0.f, d1 = 0.f, O0 = 0.f, O1 = 0.f;
    for (int c = beg; c < end; c += 64) {
        int cn = min(end - c, 64);
        int s = 0;
        float x0 = -1e30f, x1 = -1e30f;
        if (lane < cn) {
            s = ssrc[c + lane];
            float2 e = *(const float2*)&att[(size_t)s * 4];
            x0 = lrelu(e.x + er0);
            x1 = lrelu(e.y + er1);
        }
        float cm0 = x0, cm1 = x1;
#pragma unroll
        for (int o = 32; o; o >>= 1) {
            cm0 = fmaxf(cm0, __shfl_xor(cm0, o, 64));
            cm1 = fmaxf(cm1, __shfl_xor(cm1, o, 64));
        }
        float nm0 = fmaxf(m0, cm0), nm1 = fmaxf(m1, cm1);
        float p0 = (lane < cn) ? __expf(x0 - nm0) : 0.f;
        float p1 = (lane < cn) ? __expf(x1 - nm1) : 0.f;
        float cd0 = p0, cd1 = p1;
#pragma unroll
        for (int o = 32; o; o >>= 1) {
            cd0 += __shfl_xor(cd0, o, 64);
            cd1 += __shfl_xor(cd1, o, 64);
        }
        float sc0 = __expf(m0 - nm0), sc1 = __expf(m1 - nm1);
        d0 = d0 * sc0 + cd0; d1 = d1 * sc1 + cd1;
        float sch = hd ? sc1 : sc0;
        O0 *= sch; O1 *= sch;
        m0 = nm0; m1 = nm1;
        pbuf[wv][0][lane] = p0;
        pbuf[wv][1][lane] = p1;
        sbuf[wv][lane] = s;
        const float* pb = pbuf[wv][hd];
        int j = par;
        for (; j + 14 < cn; j += 16) {   // 8 edges of my parity, 8 loads in flight
            u32 w[8];
#pragma unroll
            for (int t = 0; t < 8; t++)
                w[t] = *(const u32*)&h[(size_t)sbuf[wv][j + 2 * t] * 64 + 2 * i];
#pragma unroll
            for (int t = 0; t < 8; t++) {
                float q = pb[j + 2 * t];
                O0 += q * h2f((u16)w[t]);
                O1 += q * h2f((u16)(w[t] >> 16));
            }
        }
        if (j + 6 < cn) {                // 4 edges of my parity
            u32 w[4];
#pragma unroll
            for (int t = 0; t < 4; t++)
                w[t] = *(const u32*)&h[(size_t)sbuf[wv][j + 2 * t] * 64 + 2 * i];
#pragma unroll
            for (int t = 0; t < 4; t++) {
                float q = pb[j + 2 * t];
                O0 += q * h2f((u16)w[t]);
                O1 += q * h2f((u16)(w[t] >> 16));
            }
            j += 8;
        }
        for (; j < cn; j += 2) {
            u32 w = *(const u32*)&h[(size_t)sbuf[wv][j] * 64 + 2 * i];
            float q = pb[j];
            O0 += q * h2f((u16)w);
            O1 += q * h2f((u16)(w >> 16));
        }
    }
    O0 += __shfl_xor(O0, 32, 64);        // combine edge parities
    O1 += __shfl_xor(O1, 32, 64);
    if (lane < 32) {
        float dd = hd ? d1 : d0;
        float o0 = (end > beg) ? O0 / dd : 0.f;
        float o1 = (end > beg) ? O1 / dd : 0.f;
        u32 rv = *(const u32*)&hp[(size_t)node * 64 + 2 * i];
        float a0 = tanhf(o0 + bf2f((u16)rv));
        float a1 = tanhf(o1 + bf2f((u16)(rv >> 16)));
        *(u32*)&hp[(size_t)node * 64 + 2 * i] = pack2(a0, a1);
    }
}

// ---------------- launch ----------------
extern "C" void kernel_launch(void* const* d_in, const int* in_sizes, int n_in,
                              void* d_out, int out_size, void* d_ws, size_t ws_size,
                              hipStream_t stream) {
    const int N = NN, E = NE;
    const void* fvs = d_in[0];
    const void* pos = d_in[1];
    const int* src = (const int*)d_in[2];
    const int* dst = (const int*)d_in[3];
    const void* gW[3]  = {d_in[4],  d_in[8],  d_in[12]};
    const void* gal[3] = {d_in[5],  d_in[9],  d_in[13]};
    const void* gar[3] = {d_in[6],  d_in[10], d_in[14]};
    const void* grW[3] = {d_in[7],  d_in[11], d_in[15]};
    const void* pW[2]  = {d_in[16], d_in[19]};
    const void* pal[2] = {d_in[17], d_in[20]};
    const void* par[2] = {d_in[18], d_in[21]};

    // packed weight geometry (u16 counts)
    const size_t GSZ = (size_t)192 * 128 * 2;   // u16 per gat matrix (hi+lo)
    const size_t PSZ = (size_t)64 * 64 * 2;
    const size_t CS  = 6 * GSZ + 2 * PSZ;       // u16 per copy (311296, 16B-divisible)

    // ---- workspace layout (wrap-safe) ----
    auto al256 = [](size_t b) { return (b + 255) & ~(size_t)255; };
    size_t sz_dmode = al256(4);
    size_t sz_bsum  = al256(32 * 4);
    size_t sz_bcur  = al256(256 * 4);
    size_t sz_att   = al256((size_t)N * 4 * 4);   // also hosts cnt during CSR build
    size_t sz_off   = al256((size_t)(N + 1) * 4);
    size_t sz_ssrc  = al256((size_t)E * 4);
    size_t sz_hs    = al256((size_t)N * 128 * 2);
    size_t sz_hp    = al256((size_t)N * 64 * 2);
    size_t sz_wpk   = al256(CS * NCPY * 2);       // NCPY replicated copies
    size_t need = sz_dmode + sz_bsum + sz_bcur + sz_att + sz_off + sz_ssrc
                + sz_hs + sz_hp + sz_wpk;
    int bad = (need > ws_size) ? 1 : 0;

    size_t cur = 0;
    auto alloc = [&](size_t bytes) {
        if (cur + bytes > ws_size) cur = 0;
        char* p = (char*)d_ws + cur;
        if (bytes <= ws_size) cur += bytes;
        return p;
    };
    int* dmode  = (int*)alloc(sz_dmode);
    int* bsum   = (int*)alloc(sz_bsum);
    int* bcur   = (int*)alloc(sz_bcur);
    float* att  = (float*)alloc(sz_att);
    int* off    = (int*)alloc(sz_off);
    int* ssrc   = (int*)alloc(sz_ssrc);
    u16* hs     = (u16*)alloc(sz_hs);
    u16* hp     = (u16*)alloc(sz_hp);
    u16* wpk    = (u16*)alloc(sz_wpk);

    // packed weight slots within copy 0: [gW0, grW0, gW1, grW1, gW2, grW2, pW0, pW1]
    u16* Bp[8];
    for (int m = 0; m < 6; m++) Bp[m] = wpk + (size_t)m * GSZ;
    Bp[6] = wpk + 6 * GSZ;
    Bp[7] = Bp[6] + PSZ;

    // cnt aliases att; tmp (binned edges, 3.2MB) aliases hs (dead before first GEMM).
    int* cnt = (int*)att;
    u32* tmp = (u32*)hs;

    void* H = d_out;   // transformed features in d_out: fp16 [N,128]; dead at end

    hipMemsetAsync(cnt, 0, (size_t)N * 4, stream);

    k_detect<<<1, 256, 0, stream>>>((const u16*)fvs, dmode);

    PWArgs pwa;
    pwa.src[0] = gW[0]; pwa.src[1] = grW[0];
    pwa.src[2] = gW[1]; pwa.src[3] = grW[1];
    pwa.src[4] = gW[2]; pwa.src[5] = grW[2];
    pwa.src[6] = pW[0]; pwa.src[7] = pW[1];
    for (int m = 0; m < 8; m++) {
        pwa.dst[m] = Bp[m];
        pwa.K[m] = (m < 6) ? 192 : 64;
        pwa.BM[m] = (m < 6) ? 128 : 64;
    }
    k_prepw<<<64, 256, 0, stream>>>(pwa, dmode);
    // clone copy 0 -> copies 1..NCPY-1 (vectorized; CS u16 = CS/8 uint4 per copy)
    {
        int nq = (int)(CS / 8);            // uint4 per copy
        int tot = nq * (NCPY - 1);
        k_wcopy<<<(tot + 255) / 256, 256, 0, stream>>>((u32*)wpk, nq, nq);
    }

    int eb = (E + 255) / 256;
    int nbS = (N + 2047) / 2048;
    int nbk = (N + BKT - 1) / BKT;
    k_hist<<<eb, 256, 0, stream>>>(dst, cnt, E);
    k_scan1<<<nbS, 256, 0, stream>>>(cnt, off, bsum, N);
    k_scan2<<<nbS, 256, 0, stream>>>(bsum, off, N, nbS);
    k_binit<<<1, 256, 0, stream>>>(off, bcur, nbk);
    k_fillA<<<(E + FBLK - 1) / FBLK, 256, 0, stream>>>(src, dst, bcur, tmp, E);
    k_fillB<<<nbk, 256, 0, stream>>>(off, tmp, ssrc, N);

    k_init<<<(N * 64 + 255) / 256, 256, 0, stream>>>(pos, hp, dmode, N * 64);

    int gb = (N + 63) / 64;
    int nb = (N + 3) / 4;
    int cs = (int)CS;

    // ---- layer 0 ----
    k_gemm<128, true, true><<<gb, 256, 0, stream>>>(fvs, hp, Bp[0], Bp[1], H, hs, att, gal[0], gar[0], N, 192, 128, dmode, 1, cs);
    k_edge_gat2<<<nb, 256, 0, stream>>>(off, ssrc, (u16*)H, att, hs, hs, N);
    k_gemm<64, false, true><<<gb, 256, 0, stream>>>(hp, nullptr, Bp[6], nullptr, H, nullptr, att, pal[0], par[0], N, 64, 64, dmode, 0, cs);
    k_edge_pg2<<<nb, 256, 0, stream>>>(off, ssrc, (u16*)H, att, hp, N);

    // ---- layer 1 ----
    k_gemm<128, true, true><<<gb, 256, 0, stream>>>(hs, hp, Bp[2], Bp[3], H, hs, att, gal[1], gar[1], N, 192, 128, dmode, 0, cs);
    k_edge_gat2<<<nb, 256, 0, stream>>>(off, ssrc, (u16*)H, att, hs, hs, N);
    k_gemm<64, false, true><<<gb, 256, 0, stream>>>(hp, nullptr, Bp[7], nullptr, H, nullptr, att, pal[1], par[1], N, 64, 64, dmode, 0, cs);
    k_edge_pg2<<<nb, 256, 0, stream>>>(off, ssrc, (u16*)H, att, hp, N);  // hp = pg1 out (tanh)

    // ---- output layer (fp16 H) ----
    k_gemm<128, true, true><<<gb, 256, 0, stream>>>(hs, hp, Bp[4], Bp[5], H, hs, att, gal[2], gar[2], N, 192, 128, dmode, 0, cs);
    // final mean written in-place into hs rows as f32 (row = 256B = 64 floats)
    k_edge_gat_f<<<nb, 256, 0, stream>>>(off, ssrc, (u16*)H, att, hs, (float*)hs, N);

    // H (= d_out) now dead; materialize outputs as f32.
    hipMemcpyAsync((float*)d_out, (float*)hs, (size_t)N * 64 * 4, hipMemcpyDeviceToDevice, stream);
    k_cvt<<<(N * 64 + 255) / 256, 256, 0, stream>>>(hp, (float*)d_out + (size_t)N * 64, N * 64);

    // Diagnostic: if workspace too small, out[0] reads ~100000 + MB*1000.
    if (bad) {
        float v = 100000.f + 1000.f * (float)(ws_size >> 20);
        k_tracer<<<1, 64, 0, stream>>>((float*)d_out, v);
    }
}

// Round 17
// 558.652 us; speedup vs baseline: 1.0421x; 1.0090x over previous
//
#include <hip/hip_runtime.h>

#define NN 50000
#define NE 800000
#define FBLK 8192
#define BKT 256
#define NCPY 8

typedef unsigned short u16;
typedef unsigned int u32;

typedef float f32x4 __attribute__((ext_vector_type(4)));
typedef __bf16 bf16x8 __attribute__((ext_vector_type(8)));
static_assert(sizeof(bf16x8) == 16, "bf16x8 must be 16B");

__device__ __forceinline__ float bf2f(u16 u) {
    u32 x = ((u32)u) << 16;
    return __uint_as_float(x);
}
__device__ __forceinline__ u16 f2bf(float f) {
    u32 x = __float_as_uint(f);
    u32 r = (x + 0x7fffu + ((x >> 16) & 1u)) >> 16;  // round-nearest-even
    return (u16)r;
}
__device__ __forceinline__ u32 pack2(float a, float b) {
    return (u32)f2bf(a) | ((u32)f2bf(b) << 16);
}
// fp16 (IEEE half) pack/unpack: H tensor is fp16 (2^-11 rel err vs bf16's 2^-8).
__device__ __forceinline__ u16 f2h(float f) {
    _Float16 h = (_Float16)f;
    union { _Float16 h; u16 u; } c; c.h = h;
    return c.u;
}
__device__ __forceinline__ float h2f(u16 u) {
    union { u16 u; _Float16 h; } c; c.u = u;
    return (float)c.h;
}
__device__ __forceinline__ uint4 packu4(const u16* h) {
    uint4 u;
    u.x = (u32)h[0] | ((u32)h[1] << 16);
    u.y = (u32)h[2] | ((u32)h[3] << 16);
    u.z = (u32)h[4] | ((u32)h[5] << 16);
    u.w = (u32)h[6] | ((u32)h[7] << 16);
    return u;
}
__device__ __forceinline__ float ldf(const void* p, size_t idx, int mode) {
    return mode ? bf2f(((const u16*)p)[idx]) : ((const float*)p)[idx];
}
__device__ __forceinline__ float lrelu(float x) { return x > 0.f ? x : 0.2f * x; }

// D = A.B + C ; A/B frags: 8 contiguous k per lane (k-group = lane>>4), lane&15 = row(A)/col(B)
// D: col = lane&15, row = (lane>>4)*4 + reg   [measured m89/m91]
__device__ __forceinline__ f32x4 mfma16(uint4 a, uint4 b, f32x4 c) {
    union { uint4 u; bf16x8 b; } ua, ub;
    ua.u = a; ub.u = b;
    return __builtin_amdgcn_mfma_f32_16x16x32_bf16(ua.b, ub.b, c, 0, 0, 0);
}

// ---------------- diagnostics ----------------
__global__ void k_tracer(float* out, float v) {
    if (threadIdx.x == 0 && blockIdx.x == 0) out[0] = v;
}

// ---------------- dtype detect (0 = f32 inputs, 1 = bf16 inputs) ----------------
__global__ void k_detect(const u16* __restrict__ fvs, int* __restrict__ mode) {
    __shared__ int cnt[256];
    int t = threadIdx.x;
    int bad = 0;
    for (int i = 0; i < 16; i++) {
        u16 u = fvs[(size_t)(t * 16 + i) * 2];
        int e = (u >> 7) & 0xff;
        if (e == 255 || e >= 134 || e <= 100) bad++;
    }
    cnt[t] = bad;
    __syncthreads();
    for (int d = 128; d; d >>= 1) {
        if (t < d) cnt[t] += cnt[t + d];
        __syncthreads();
    }
    if (t == 0) *mode = (cnt[0] > 2048) ? 0 : 1;
}

// ---------------- CSR build ----------------
__global__ void k_hist(const int* __restrict__ dst, int* __restrict__ cnt, int E) {
    int e = blockIdx.x * blockDim.x + threadIdx.x;
    if (e < E) atomicAdd(&cnt[dst[e]], 1);
}

// Multi-block scan, 2048 elems/block (8/thread via int4).
__global__ void k_scan1(const int* __restrict__ cnt, int* __restrict__ off,
                        int* __restrict__ bsum, int N) {
    __shared__ int wsum[4];
    int t = threadIdx.x;
    int base = blockIdx.x * 2048 + t * 8;
    int e[8];
    if (base + 8 <= N) {
        int4 v0 = *(const int4*)&cnt[base];
        int4 v1 = *(const int4*)&cnt[base + 4];
        e[0] = v0.x; e[1] = v0.y; e[2] = v0.z; e[3] = v0.w;
        e[4] = v1.x; e[5] = v1.y; e[6] = v1.z; e[7] = v1.w;
    } else {
#pragma unroll
        for (int i = 0; i < 8; i++) e[i] = (base + i < N) ? cnt[base + i] : 0;
    }
    int s = 0;
    int ps[8];
#pragma unroll
    for (int i = 0; i < 8; i++) { ps[i] = s; s += e[i]; }
    int lane = t & 63, wv = t >> 6;
    int sc = s;
#pragma unroll
    for (int o = 1; o < 64; o <<= 1) {
        int u = __shfl_up(sc, o, 64);
        if (lane >= o) sc += u;
    }
    if (lane == 63) wsum[wv] = sc;
    __syncthreads();
    int woff = 0;
    for (int w = 0; w < wv; w++) woff += wsum[w];
    int ex = woff + sc - s;   // exclusive prefix of this thread within block
#pragma unroll
    for (int i = 0; i < 8; i++) ps[i] += ex;
    if (base + 8 <= N) {
        *(int4*)&off[base] = make_int4(ps[0], ps[1], ps[2], ps[3]);
        *(int4*)&off[base + 4] = make_int4(ps[4], ps[5], ps[6], ps[7]);
    } else {
#pragma unroll
        for (int i = 0; i < 8; i++)
            if (base + i < N) off[base + i] = ps[i];
    }
    if (t == 255) bsum[blockIdx.x] = woff + sc;   // block total
}

__global__ void k_scan2(const int* __restrict__ bsum, int* __restrict__ off,
                        int N, int nb) {
    int b = blockIdx.x, t = threadIdx.x;
    int boff = 0;
    for (int i = 0; i < b; i++) boff += bsum[i];   // uniform, <=24 iters
    int base = b * 2048 + t * 8;
    if (b > 0) {
        if (base + 8 <= N) {
            int4 a = *(int4*)&off[base];
            int4 c = *(int4*)&off[base + 4];
            a.x += boff; a.y += boff; a.z += boff; a.w += boff;
            c.x += boff; c.y += boff; c.z += boff; c.w += boff;
            *(int4*)&off[base] = a;
            *(int4*)&off[base + 4] = c;
        } else {
#pragma unroll
            for (int i = 0; i < 8; i++)
                if (base + i < N) off[base + i] += boff;
        }
    }
    if (b == nb - 1 && t == 255) off[N] = boff + bsum[b];
}

// ---- CSR fill via two-pass LDS multisplit ----
__global__ void k_binit(const int* __restrict__ off, int* __restrict__ bcur, int nbk) {
    int b = threadIdx.x;
    if (b < nbk) bcur[b] = off[b * BKT];
    else if (b < 256) bcur[b] = 0;
}

__launch_bounds__(256)
__global__ void k_fillA(const int* __restrict__ src, const int* __restrict__ dst,
                        int* __restrict__ bcur, u32* __restrict__ tmp, int E) {
    __shared__ int hist[256];
    __shared__ int lbase[256];
    __shared__ int gbase[256];
    __shared__ int lcur[256];
    __shared__ u32 outrec[FBLK];
    __shared__ unsigned char bslot[FBLK];
    int t = threadIdx.x;
    int e0 = blockIdx.x * FBLK;
    int bn = min(E - e0, FBLK);
    hist[t] = 0;
    __syncthreads();
    for (int i = t; i < bn; i += 256)
        atomicAdd(&hist[dst[e0 + i] >> 8], 1);
    __syncthreads();
    if (t == 0) {
        int run = 0;
        for (int b = 0; b < 256; b++) { lbase[b] = run; run += hist[b]; }
    }
    __syncthreads();
    lcur[t] = lbase[t];
    gbase[t] = hist[t] ? atomicAdd(&bcur[t], hist[t]) : 0;
    __syncthreads();
    for (int i = t; i < bn; i += 256) {
        int d = dst[e0 + i];
        int s = src[e0 + i];
        int b = d >> 8;
        int slot = atomicAdd(&lcur[b], 1);
        outrec[slot] = (u32)s | ((u32)(d & 255) << 24);   // src < 2^24
        bslot[slot] = (unsigned char)b;
    }
    __syncthreads();
    for (int i = t; i < bn; i += 256) {
        int b = bslot[i];
        tmp[gbase[b] + (i - lbase[b])] = outrec[i];       // contiguous bucket runs
    }
}

__launch_bounds__(256)
__global__ void k_fillB(const int* __restrict__ off, const u32* __restrict__ tmp,
                        int* __restrict__ ssrc, int N) {
    __shared__ int lcur[BKT];
    __shared__ u32 outv[FBLK];
    int b = blockIdx.x, t = threadIdx.x;
    int n0 = b * BKT;
    int nn = min(N - n0, BKT);
    int nbeg = off[n0], nend = off[n0 + nn];
    int sz = nend - nbeg;
    for (int i = t; i < nn; i += 256) lcur[i] = off[n0 + i] - nbeg;
    __syncthreads();
    if (sz <= FBLK) {
        for (int i = t; i < sz; i += 256) {
            u32 r = tmp[nbeg + i];
            int slot = atomicAdd(&lcur[r >> 24], 1);
            outv[slot] = r & 0x00FFFFFFu;
        }
        __syncthreads();
        for (int i = t; i < sz; i += 256)
            ssrc[nbeg + i] = (int)outv[i];
    } else {  // bucket overflow fallback (correctness only)
        for (int i = t; i < sz; i += 256) {
            u32 r = tmp[nbeg + i];
            int slot = atomicAdd(&lcur[r >> 24], 1);
            ssrc[nbeg + slot] = (int)(r & 0x00FFFFFFu);
        }
    }
}

// ---------------- init: hp = bf16(pos) ----------------
__global__ void k_init(const void* __restrict__ pos, u16* __restrict__ hp,
                       const int* __restrict__ dmode, int n64) {
    int i = blockIdx.x * blockDim.x + threadIdx.x;
    if (i >= n64) return;
    int mode = *dmode;
    hp[i] = mode ? ((const u16*)pos)[i] : f2bf(((const float*)pos)[i]);
}

// ---------------- hp (bf16) -> f32 ----------------
__global__ void k_cvt(const u16* __restrict__ in, float* __restrict__ out, int n) {
    int i = blockIdx.x * blockDim.x + threadIdx.x;
    if (i < n) out[i] = bf2f(in[i]);
}

// ---------------- weight pre-split: W -> packed {hi,lo} bf16 (copy 0 only) ----------------
struct PWArgs {
    const void* src[8];
    u16* dst[8];
    int K[8];
    int BM[8];
};

__global__ void k_prepw(PWArgs a, const int* __restrict__ dmode) {
    int mode = *dmode;
    int g = blockIdx.x * blockDim.x + threadIdx.x;
    int stride = gridDim.x * blockDim.x;
    for (int m = 0; m < 8; m++) {
        int bm = a.BM[m];
        int bmsh = (bm == 128) ? 7 : 6;
        int n = a.K[m] * bm;
        u16* d = a.dst[m];
        const void* s = a.src[m];
        for (int i = g; i < n; i += stride) {
            int k = i >> bmsh, c = i & (bm - 1);
            float v = mode ? bf2f(((const u16*)s)[i]) : ((const float*)s)[i];
            u16 hi = f2bf(v);
            u16 lo = f2bf(v - bf2f(hi));
            size_t o = ((size_t)((k >> 5) * 2) * bm + c) * 32 + (k & 31);
            d[o] = hi;
            d[o + (size_t)bm * 32] = lo;
        }
    }
}

// Vectorized clone of packed-weight copy 0 into copies 1..NCPY-1 (uint4 = 16B units).
__global__ void k_wcopy(u32* __restrict__ wpk, int nq, int cq) {
    // nq = uint4 count of one copy; cq = uint4 stride between copies
    int i = blockIdx.x * blockDim.x + threadIdx.x;
    if (i >= nq * (NCPY - 1)) return;
    int cc = i / nq + 1;
    int q = i - (cc - 1) * nq;
    uint4* p = (uint4*)wpk;
    p[(size_t)cc * cq + q] = p[q];
}

// ---------------- MFMA GEMM + fused el/er epilogue ----------------
// Round-8 structure + B replication. Copy select = blockIdx & 7: consecutive
// blockIdx round-robin across the 8 XCDs, so this pins copy k to XCD k --
// each private L2 caches exactly one 622KB copy, and the 8 copies occupy
// disjoint L3 line sets (no same-line multicast hotspot).
template <int BM, bool HASB2, bool C1H>
__launch_bounds__(256, 4)
__global__ void k_gemm(const void* A1, const u16* __restrict__ A2,
                       const u16* __restrict__ B1p, const u16* __restrict__ B2p,
                       void* __restrict__ C1, u16* C2, float* __restrict__ att,
                       const void* __restrict__ al, const void* __restrict__ ar,
                       int N, int K, int s1, const int* __restrict__ dmode,
                       int a1_input, int cstride) {
    constexpr int NR = BM / 32;            // 16-col frag tiles per wave (4 or 2)
    constexpr int NMAT = HASB2 ? 2 : 1;

    const int mode = *dmode;
    const int a1f32 = (a1_input && mode == 0) ? 1 : 0;
    const int bsplit = (mode == 0) ? 1 : 0;

    const int tid = threadIdx.x;
    const int lane = tid & 63;
    const int wid = tid >> 6;
    const int l15 = lane & 15, l4 = lane >> 4;
    const int r0 = blockIdx.x * 64;
    const int wrow0 = (wid >> 1) * 32;
    const int wcol0 = (wid & 1) * (BM / 2);
    const int ko = l4 * 8;                 // k offset of my 8-elem fragment

    // XCD-aligned B copy select (xcd = blockIdx % 8 on MI355X round-robin dispatch)
    const size_t coff = (size_t)(blockIdx.x & (NCPY - 1)) * (size_t)cstride;
    const u16* b1 = B1p + coff;
    const u16* b2 = HASB2 ? (B2p + coff) : nullptr;

    int frow[2];
#pragma unroll
    for (int m = 0; m < 2; m++) {
        int r = r0 + wrow0 + m * 16 + l15;
        frow[m] = r < N ? r : N - 1;
    }

    f32x4 acc[NMAT][2][NR];
    const f32x4 fz = {0.f, 0.f, 0.f, 0.f};
#pragma unroll
    for (int m2 = 0; m2 < NMAT; m2++)
#pragma unroll
        for (int m = 0; m < 2; m++)
#pragma unroll
            for (int n = 0; n < NR; n++) acc[m2][m][n] = fz;

    const int NKT = K >> 5;
    const int rot = (int)((u32)(blockIdx.x >> 3) % (u32)NKT);  // desync within an XCD
    for (int tt = 0; tt < NKT; tt++) {
        int kt = tt + rot;
        if (kt >= NKT) kt -= NKT;
        const int k0 = kt << 5;
        const int doAlo = (a1f32 && k0 < 128) ? 1 : 0;

        uint4 ah[2], alo[2];
#pragma unroll
        for (int m = 0; m < 2; m++) {
            if (k0 >= 128) {               // A2 region (always bf16, stride 64)
                ah[m] = *(const uint4*)(A2 + (size_t)frow[m] * 64 + (k0 - 128) + ko);
            } else if (!a1f32) {           // A1 bf16
                ah[m] = *(const uint4*)((const u16*)A1 + (size_t)frow[m] * s1 + k0 + ko);
            } else {                       // A1 f32: load 32B, split hi/lo in regs
                const float* p = (const float*)A1 + (size_t)frow[m] * s1 + k0 + ko;
                union { uint4 u[2]; float f[8]; } fa;
                fa.u[0] = *(const uint4*)p;
                fa.u[1] = *(const uint4*)(p + 4);
                u16 hi[8], lo[8];
#pragma unroll
                for (int i = 0; i < 8; i++) {
                    hi[i] = f2bf(fa.f[i]);
                    lo[i] = f2bf(fa.f[i] - bf2f(hi[i]));   // exact residual (Sterbenz)
                }
                ah[m] = packu4(hi);
                alo[m] = packu4(lo);
            }
        }

        const size_t bbase = ((size_t)kt * 2) * BM * 32 + (size_t)l4 * 8;
#pragma unroll
        for (int n = 0; n < NR; n++) {
            const int c = wcol0 + n * 16 + l15;
            const size_t co = (size_t)c * 32;
#pragma unroll
            for (int m2 = 0; m2 < NMAT; m2++) {
                const u16* bp = (m2 == 0 ? b1 : b2) + bbase + co;
                uint4 bh = *(const uint4*)bp;
#pragma unroll
                for (int m = 0; m < 2; m++)
                    acc[m2][m][n] = mfma16(ah[m], bh, acc[m2][m][n]);
                if (bsplit) {
                    uint4 bl = *(const uint4*)(bp + (size_t)BM * 32);
#pragma unroll
                    for (int m = 0; m < 2; m++)
                        acc[m2][m][n] = mfma16(ah[m], bl, acc[m2][m][n]);
                }
                if (doAlo) {
#pragma unroll
                    for (int m = 0; m < 2; m++)
                        acc[m2][m][n] = mfma16(alo[m], bh, acc[m2][m][n]);
                }
            }
        }
    }

    __syncthreads();   // in-place safety: all block A-reads done before C2 writes

    // ---- epilogue: C stores + fused el/er ----
    float alc[NR], arc[NR];
#pragma unroll
    for (int n = 0; n < NR; n++) {
        int c = wcol0 + n * 16 + l15;
        alc[n] = ldf(al, c, mode);
        arc[n] = ldf(ar, c, mode);
    }
    const int hc = wid & 1;
#pragma unroll
    for (int m = 0; m < 2; m++) {
#pragma unroll
        for (int r = 0; r < 4; r++) {
            const int gr = r0 + wrow0 + m * 16 + l4 * 4 + r;
            float el = 0.f, er = 0.f;
#pragma unroll
            for (int n = 0; n < NR; n++) {
                float v = acc[0][m][n][r];
                el = fmaf(v, alc[n], el);
                er = fmaf(v, arc[n], er);
            }
#pragma unroll
            for (int o = 1; o <= 8; o <<= 1) {   // reduce the 16 col-lanes (same row)
                el += __shfl_xor(el, o, 64);
                er += __shfl_xor(er, o, 64);
            }
            if (gr < N) {
#pragma unroll
                for (int n = 0; n < NR; n++) {
                    const int c = wcol0 + n * 16 + l15;
                    float v = acc[0][m][n][r];
                    if constexpr (C1H)
                        ((u16*)C1)[(size_t)gr * BM + c] = f2h(v);
                    else
                        ((float*)C1)[(size_t)gr * BM + c] = v;
                    if constexpr (HASB2)
                        C2[(size_t)gr * 128 + c] = f2bf(acc[1][m][n][r]);
                }
                if (l15 == 0) {
                    att[(size_t)gr * 4 + hc] = el;
                    att[(size_t)gr * 4 + 2 + hc] = er;
                }
            }
        }
    }
}

// ---------------- edge aggregation ----------------
// gat layers 0/1: fp16 H, wave per node, lane owns feature elems {2l, 2l+1}
// (head = l>>5). Gather unroll-8: 8 independent row loads in flight per wave.
__global__ void k_edge_gat2(const int* __restrict__ off, const int* __restrict__ ssrc,
                            const u16* __restrict__ h, const float* __restrict__ att,
                            const u16* __restrict__ res, u16* __restrict__ outf, int N) {
    __shared__ float pbuf[4][2][64];
    __shared__ int sbuf[4][64];
    int wv = threadIdx.x >> 6;
    int node = blockIdx.x * 4 + wv;
    int lane = threadIdx.x & 63;
    if (node >= N) return;
    const int hd = lane >> 5;            // head of my elems (2*lane)>>6
    int beg = off[node], end = off[node + 1];
    float4 a4 = *(const float4*)&att[(size_t)node * 4];
    float er0 = a4.z, er1 = a4.w;
    float m0 = -1e30f, m1 = -1e30f, d0 = 0.f, d1 = 0.f, O0 = 0.f, O1 = 0.f;
    for (int c = beg; c < end; c += 64) {
        int cn = min(end - c, 64);
        int s = 0;
        float x0 = -1e30f, x1 = -1e30f;
        if (lane < cn) {
            s = ssrc[c + lane];
            float2 e = *(const float2*)&att[(size_t)s * 4];
            x0 = lrelu(e.x + er0);
            x1 = lrelu(e.y + er1);
        }
        float cm0 = x0, cm1 = x1;
#pragma unroll
        for (int o = 32; o; o >>= 1) {
            cm0 = fmaxf(cm0, __shfl_xor(cm0, o, 64));
            cm1 = fmaxf(cm1, __shfl_xor(cm1, o, 64));
        }
        float nm0 = fmaxf(m0, cm0), nm1 = fmaxf(m1, cm1);
        float p0 = (lane < cn) ? __expf(x0 - nm0) : 0.f;
        float p1 = (lane < cn) ? __expf(x1 - nm1) : 0.f;
        float cd0 = p0, cd1 = p1;
#pragma unroll
        for (int o = 32; o; o >>= 1) {
            cd0 += __shfl_xor(cd0, o, 64);
            cd1 += __shfl_xor(cd1, o, 64);
        }
        float sc0 = __expf(m0 - nm0), sc1 = __expf(m1 - nm1);
        d0 = d0 * sc0 + cd0; d1 = d1 * sc1 + cd1;
        float sch = hd ? sc1 : sc0;
        O0 *= sch; O1 *= sch;
        m0 = nm0; m1 = nm1;
        pbuf[wv][0][lane] = p0;
        pbuf[wv][1][lane] = p1;
        sbuf[wv][lane] = s;
        const float* pb = pbuf[wv][hd];
        int j = 0;
        for (; j + 7 < cn; j += 8) {     // 8 loads in flight
            u32 w[8];
#pragma unroll
            for (int t = 0; t < 8; t++)
                w[t] = *(const u32*)&h[(size_t)sbuf[wv][j + t] * 128 + 2 * lane];
#pragma unroll
            for (int t = 0; t < 8; t++) {
                float q = pb[j + t];
                O0 += q * h2f((u16)w[t]);
                O1 += q * h2f((u16)(w[t] >> 16));
            }
        }
        if (j + 3 < cn) {
            u32 w[4];
#pragma unroll
            for (int t = 0; t < 4; t++)
                w[t] = *(const u32*)&h[(size_t)sbuf[wv][j + t] * 128 + 2 * lane];
#pragma unroll
            for (int t = 0; t < 4; t++) {
                float q = pb[j + t];
                O0 += q * h2f((u16)w[t]);
                O1 += q * h2f((u16)(w[t] >> 16));
            }
            j += 4;
        }
        for (; j < cn; j++) {
            u32 w = *(const u32*)&h[(size_t)sbuf[wv][j] * 128 + 2 * lane];
            float q = pb[j];
            O0 += q * h2f((u16)w);
            O1 += q * h2f((u16)(w >> 16));
        }
    }
    float dd = hd ? d1 : d0;
    float o0 = (end > beg) ? O0 / dd : 0.f;
    float o1 = (end > beg) ? O1 / dd : 0.f;
    u32 rv = *(const u32*)&res[(size_t)node * 128 + 2 * lane];
    float a0 = o0 + bf2f((u16)rv);
    float a1 = o1 + bf2f((u16)(rv >> 16));
    a0 = a0 > 0.f ? a0 : (__expf(a0) - 1.f);  // elu
    a1 = a1 > 0.f ? a1 : (__expf(a1) - 1.f);
    *(u32*)&outf[(size_t)node * 128 + 2 * lane] = pack2(a0, a1);
}

// Final layer (mean over heads): fp16 H, edge-parity split, gather unroll-8.
__global__ void k_edge_gat_f(const int* __restrict__ off, const int* __restrict__ ssrc,
                             const u16* __restrict__ h, const float* __restrict__ att,
                             const u16* __restrict__ res, float* __restrict__ outs, int N) {
    __shared__ float pbuf[4][2][64];
    __shared__ int sbuf[4][64];
    int wv = threadIdx.x >> 6;
    int node = blockIdx.x * 4 + wv;
    int lane = threadIdx.x & 63;
    if (node >= N) return;
    const int par = lane >> 5;
    const int i = lane & 31;
    const int hd = i >> 4;               // head of elems 4i..4i+3
    int beg = off[node], end = off[node + 1];
    float4 a4 = *(const float4*)&att[(size_t)node * 4];
    float er0 = a4.z, er1 = a4.w;
    float m0 = -1e30f, m1 = -1e30f, d0 = 0.f, d1 = 0.f;
    float O[4] = {0.f, 0.f, 0.f, 0.f};
    for (int c = beg; c < end; c += 64) {
        int cn = min(end - c, 64);
        int s = 0;
        float x0 = -1e30f, x1 = -1e30f;
        if (lane < cn) {
            s = ssrc[c + lane];
            float2 e = *(const float2*)&att[(size_t)s * 4];
            x0 = lrelu(e.x + er0);
            x1 = lrelu(e.y + er1);
        }
        float cm0 = x0, cm1 = x1;
#pragma unroll
        for (int o = 32; o; o >>= 1) {
            cm0 = fmaxf(cm0, __shfl_xor(cm0, o, 64));
            cm1 = fmaxf(cm1, __shfl_xor(cm1, o, 64));
        }
        float nm0 = fmaxf(m0, cm0), nm1 = fmaxf(m1, cm1);
        float p0 = (lane < cn) ? __expf(x0 - nm0) : 0.f;
        float p1 = (lane < cn) ? __expf(x1 - nm1) : 0.f;
        float cd0 = p0, cd1 = p1;
#pragma unroll
        for (int o = 32; o; o >>= 1) {
            cd0 += __shfl_xor(cd0, o, 64);
            cd1 += __shfl_xor(cd1, o, 64);
        }
        float sc0 = __expf(m0 - nm0), sc1 = __expf(m1 - nm1);
        d0 = d0 * sc0 + cd0; d1 = d1 * sc1 + cd1;
        float sch = hd ? sc1 : sc0;
#pragma unroll
        for (int k = 0; k < 4; k++) O[k] *= sch;
        m0 = nm0; m1 = nm1;
        pbuf[wv][0][lane] = p0;
        pbuf[wv][1][lane] = p1;
        sbuf[wv][lane] = s;
        const float* pb = pbuf[wv][hd];
        int j = par;
        for (; j + 14 < cn; j += 16) {   // 8 edges of my parity, 8 loads in flight
            uint2 w[8];
#pragma unroll
            for (int t = 0; t < 8; t++)
                w[t] = *(const uint2*)&h[(size_t)sbuf[wv][j + 2 * t] * 128 + 4 * i];
#pragma unroll
            for (int t = 0; t < 8; t++) {
                float q = pb[j + 2 * t];
                O[0] += q * h2f((u16)w[t].x);
                O[1] += q * h2f((u16)(w[t].x >> 16));
                O[2] += q * h2f((u16)w[t].y);
                O[3] += q * h2f((u16)(w[t].y >> 16));
            }
        }
        if (j + 6 < cn) {                // 4 edges of my parity
            uint2 w[4];
#pragma unroll
            for (int t = 0; t < 4; t++)
                w[t] = *(const uint2*)&h[(size_t)sbuf[wv][j + 2 * t] * 128 + 4 * i];
#pragma unroll
            for (int t = 0; t < 4; t++) {
                float q = pb[j + 2 * t];
                O[0] += q * h2f((u16)w[t].x);
                O[1] += q * h2f((u16)(w[t].x >> 16));
                O[2] += q * h2f((u16)w[t].y);
                O[3] += q * h2f((u16)(w[t].y >> 16));
            }
            j += 8;
        }
        for (; j < cn; j += 2) {
            uint2 w = *(const uint2*)&h[(size_t)sbuf[wv][j] * 128 + 4 * i];
            float q = pb[j];
            O[0] += q * h2f((u16)w.x);
            O[1] += q * h2f((u16)(w.x >> 16));
            O[2] += q * h2f((u16)w.y);
            O[3] += q * h2f((u16)(w.y >> 16));
        }
    }
#pragma unroll
    for (int k = 0; k < 4; k++) O[k] += __shfl_xor(O[k], 32, 64);  // combine parities
    float dd = hd ? d1 : d0;
    uint2 rv = *(const uint2*)&res[(size_t)node * 128 + 4 * i];
    float a[4];
    a[0] = bf2f((u16)rv.x);
    a[1] = bf2f((u16)(rv.x >> 16));
    a[2] = bf2f((u16)rv.y);
    a[3] = bf2f((u16)(rv.y >> 16));
#pragma unroll
    for (int k = 0; k < 4; k++) {
        float o = (end > beg) ? O[k] / dd : 0.f;
        float v = o + a[k];
        a[k] = v > 0.f ? v : (__expf(v) - 1.f);  // elu
    }
    float b[4];
#pragma unroll
    for (int k = 0; k < 4; k++) b[k] = __shfl_xor(a[k], 16, 64);  // partner head
    if (lane < 16)
        *(float4*)&outs[(size_t)node * 64 + 4 * i] =
            make_float4(0.5f * (a[0] + b[0]), 0.5f * (a[1] + b[1]),
                        0.5f * (a[2] + b[2]), 0.5f * (a[3] + b[3]));
}

// pg: fp16 H [N,64], wave per node; edge-parity split, gather unroll-8.
__global__ void k_edge_pg2(const int* __restrict__ off, const int* __restrict__ ssrc,
                           const u16* __restrict__ h, const float* __restrict__ att,
                           u16* __restrict__ hp, int N) {
    __shared__ float pbuf[4][2][64];
    __shared__ int sbuf[4][64];
    int wv = threadIdx.x >> 6;
    int node = blockIdx.x * 4 + wv;
    int lane = threadIdx.x & 63;
    if (node >= N) return;
    const int par = lane >> 5;
    const int i = lane & 31;
    const int hd = i >> 4;               // head of elems 2i,2i+1
    int beg = off[node], end = off[node + 1];
    float4 a4 = *(const float4*)&att[(size_t)node * 4];
    float er0 = a4.z, er1 = a4.w;
    float m0 = -1e30f, m1 = -1e30f, d0 = 0.f, d1 = 0.f, O0 = 0.f, O1 = 0.f;
    for (int c = beg; c < end; c += 64) {
        int cn = min(end - c, 64);
        int s = 0;
        float x0 = -1e30f, x1 = -1e30f;
        if (lane < cn) {
            s = ssrc[c + lane];
            float2 e = *(const float2*)&att[(size_t)s * 4];
            x0 = lrelu(e.x + er0);
            x1 = lrelu(e.y + er1);
        }
        float cm0 = x0, cm1 = x1;
#pragma unroll
        for (int o = 32; o; o >>= 1) {
            cm0 = fmaxf(cm0, __shfl_xor(cm0, o, 64));
            cm1 = fmaxf(cm1, __shfl_xor(cm1, o, 64));
        }
        float nm0 = fmaxf(m0, cm0), nm1 = fmaxf(m1, cm1);
        float p0 = (lane < cn) ? __expf(x0 - nm0) : 0.f;
        float p1 = (lane < cn) ? __expf(x1 - nm1) : 0.f;
        float cd0 = p0, cd1 = p1;
#pragma unroll
        for (int o = 32; o; o >>= 1) {
            cd0 += __shfl_xor(cd0, o, 64);
            cd1 += __shfl_xor(cd1, o, 64);
        }
        float sc0 = __expf(m0 - nm0), sc1 = __expf(m1 - nm1);
        d0 = d0 * sc0 + cd0; d1 = d1 * sc1 + cd1;
        float sch = hd ? sc1 : sc0;
        O0 *= sch; O1 *= sch;
        m0 = nm0; m1 = nm1;
        pbuf[wv][0][lane] = p0;
        pbuf[wv][1][lane] = p1;
        sbuf[wv][lane] = s;
        const float* pb = pbuf[wv][hd];
        int j = par;
        for (; j + 14 < cn; j += 16) {   // 8 edges of my parity, 8 loads in flight
            u32 w[8];
#pragma unroll
            for (int t = 0; t < 8; t++)
                w[t] = *(const u32*)&h[(size_t)sbuf[wv][j + 2 * t] * 64 + 2 * i];
#pragma unroll
            for (int t = 0; t < 8; t++) {
                float q = pb[j + 2 * t];
                O0 += q * h2f((u16)w[t]);
                O1 += q * h2f((u16)(w[t] >> 16));
            }
        }
        if (j + 6 < cn) {                // 4 edges of my parity
            u32 w[4];
#pragma unroll
            for (int t = 0; t < 4; t++)
                w[t] = *(const u32*)&h[(size_t)sbuf[wv][j + 2 * t] * 64 + 2 * i];
#pragma unroll
            for (int t = 0; t < 4; t++) {
                float q = pb[j + 2 * t];
                O0 += q * h2f((u16)w[t]);
                O1 += q * h2f((u16)(w[t] >> 16));
            }
            j += 8;
        }
        for (; j < cn; j += 2) {
            u32 w = *(const u32*)&h[(size_t)sbuf[wv][j] * 64 + 2 * i];
            float q = pb[j];
            O0 += q * h2f((u16)w);
            O1 += q * h2f((u16)(w >> 16));
        }
    }
    O0 += __shfl_xor(O0, 32, 64);        // combine edge parities
    O1 += __shfl_xor(O1, 32, 64);
    if (lane < 32) {
        float dd = hd ? d1 : d0;
        float o0 = (end > beg) ? O0 / dd : 0.f;
        float o1 = (end > beg) ? O1 / dd : 0.f;
        u32 rv = *(const u32*)&hp[(size_t)node * 64 + 2 * i];
        float a0 = tanhf(o0 + bf2f((u16)rv));
        float a1 = tanhf(o1 + bf2f((u16)(rv >> 16)));
        *(u32*)&hp[(size_t)node * 64 + 2 * i] = pack2(a0, a1);
    }
}

// ---------------- launch ----------------
extern "C" void kernel_launch(void* const* d_in, const int* in_sizes, int n_in,
                              void* d_out, int out_size, void* d_ws, size_t ws_size,
                              hipStream_t stream) {
    const int N = NN, E = NE;
    const void* fvs = d_in[0];
    const void* pos = d_in[1];
    const int* src = (const int*)d_in[2];
    const int* dst = (const int*)d_in[3];
    const void* gW[3]  = {d_in[4],  d_in[8],  d_in[12]};
    const void* gal[3] = {d_in[5],  d_in[9],  d_in[13]};
    const void* gar[3] = {d_in[6],  d_in[10], d_in[14]};
    const void* grW[3] = {d_in[7],  d_in[11], d_in[15]};
    const void* pW[2]  = {d_in[16], d_in[19]};
    const void* pal[2] = {d_in[17], d_in[20]};
    const void* par[2] = {d_in[18], d_in[21]};

    // packed weight geometry (u16 counts)
    const size_t GSZ = (size_t)192 * 128 * 2;   // u16 per gat matrix (hi+lo)
    const size_t PSZ = (size_t)64 * 64 * 2;
    const size_t CS  = 6 * GSZ + 2 * PSZ;       // u16 per copy (311296, 16B-divisible)

    // ---- workspace layout (wrap-safe) ----
    auto al256 = [](size_t b) { return (b + 255) & ~(size_t)255; };
    size_t sz_dmode = al256(4);
    size_t sz_bsum  = al256(32 * 4);
    size_t sz_bcur  = al256(256 * 4);
    size_t sz_att   = al256((size_t)N * 4 * 4);   // also hosts cnt during CSR build
    size_t sz_off   = al256((size_t)(N + 1) * 4);
    size_t sz_ssrc  = al256((size_t)E * 4);
    size_t sz_hs    = al256((size_t)N * 128 * 2);
    size_t sz_hp    = al256((size_t)N * 64 * 2);
    size_t sz_wpk   = al256(CS * NCPY * 2);       // NCPY replicated copies
    size_t need = sz_dmode + sz_bsum + sz_bcur + sz_att + sz_off + sz_ssrc
                + sz_hs + sz_hp + sz_wpk;
    int bad = (need > ws_size) ? 1 : 0;

    size_t cur = 0;
    auto alloc = [&](size_t bytes) {
        if (cur + bytes > ws_size) cur = 0;
        char* p = (char*)d_ws + cur;
        if (bytes <= ws_size) cur += bytes;
        return p;
    };
    int* dmode  = (int*)alloc(sz_dmode);
    int* bsum   = (int*)alloc(sz_bsum);
    int* bcur   = (int*)alloc(sz_bcur);
    float* att  = (float*)alloc(sz_att);
    int* off    = (int*)alloc(sz_off);
    int* ssrc   = (int*)alloc(sz_ssrc);
    u16* hs     = (u16*)alloc(sz_hs);
    u16* hp     = (u16*)alloc(sz_hp);
    u16* wpk    = (u16*)alloc(sz_wpk);

    // packed weight slots within copy 0: [gW0, grW0, gW1, grW1, gW2, grW2, pW0, pW1]
    u16* Bp[8];
    for (int m = 0; m < 6; m++) Bp[m] = wpk + (size_t)m * GSZ;
    Bp[6] = wpk + 6 * GSZ;
    Bp[7] = Bp[6] + PSZ;

    // cnt aliases att; tmp (binned edges, 3.2MB) aliases hs (dead before first GEMM).
    int* cnt = (int*)att;
    u32* tmp = (u32*)hs;

    void* H = d_out;   // transformed features in d_out: fp16 [N,128]; dead at end

    hipMemsetAsync(cnt, 0, (size_t)N * 4, stream);

    k_detect<<<1, 256, 0, stream>>>((const u16*)fvs, dmode);

    PWArgs pwa;
    pwa.src[0] = gW[0]; pwa.src[1] = grW[0];
    pwa.src[2] = gW[1]; pwa.src[3] = grW[1];
    pwa.src[4] = gW[2]; pwa.src[5] = grW[2];
    pwa.src[6] = pW[0]; pwa.src[7] = pW[1];
    for (int m = 0; m < 8; m++) {
        pwa.dst[m] = Bp[m];
        pwa.K[m] = (m < 6) ? 192 : 64;
        pwa.BM[m] = (m < 6) ? 128 : 64;
    }
    k_prepw<<<64, 256, 0, stream>>>(pwa, dmode);
    // clone copy 0 -> copies 1..NCPY-1 (vectorized; CS u16 = CS/8 uint4 per copy)
    {
        int nq = (int)(CS / 8);            // uint4 per copy
        int tot = nq * (NCPY - 1);
        k_wcopy<<<(tot + 255) / 256, 256, 0, stream>>>((u32*)wpk, nq, nq);
    }

    int eb = (E + 255) / 256;
    int nbS = (N + 2047) / 2048;
    int nbk = (N + BKT - 1) / BKT;
    k_hist<<<eb, 256, 0, stream>>>(dst, cnt, E);
    k_scan1<<<nbS, 256, 0, stream>>>(cnt, off, bsum, N);
    k_scan2<<<nbS, 256, 0, stream>>>(bsum, off, N, nbS);
    k_binit<<<1, 256, 0, stream>>>(off, bcur, nbk);
    k_fillA<<<(E + FBLK - 1) / FBLK, 256, 0, stream>>>(src, dst, bcur, tmp, E);
    k_fillB<<<nbk, 256, 0, stream>>>(off, tmp, ssrc, N);

    k_init<<<(N * 64 + 255) / 256, 256, 0, stream>>>(pos, hp, dmode, N * 64);

    int gb = (N + 63) / 64;
    int nb = (N + 3) / 4;
    int cs = (int)CS;

    // ---- layer 0 ----
    k_gemm<128, true, true><<<gb, 256, 0, stream>>>(fvs, hp, Bp[0], Bp[1], H, hs, att, gal[0], gar[0], N, 192, 128, dmode, 1, cs);
    k_edge_gat2<<<nb, 256, 0, stream>>>(off, ssrc, (u16*)H, att, hs, hs, N);
    k_gemm<64, false, true><<<gb, 256, 0, stream>>>(hp, nullptr, Bp[6], nullptr, H, nullptr, att, pal[0], par[0], N, 64, 64, dmode, 0, cs);
    k_edge_pg2<<<nb, 256, 0, stream>>>(off, ssrc, (u16*)H, att, hp, N);

    // ---- layer 1 ----
    k_gemm<128, true, true><<<gb, 256, 0, stream>>>(hs, hp, Bp[2], Bp[3], H, hs, att, gal[1], gar[1], N, 192, 128, dmode, 0, cs);
    k_edge_gat2<<<nb, 256, 0, stream>>>(off, ssrc, (u16*)H, att, hs, hs, N);
    k_gemm<64, false, true><<<gb, 256, 0, stream>>>(hp, nullptr, Bp[7], nullptr, H, nullptr, att, pal[1], par[1], N, 64, 64, dmode, 0, cs);
    k_edge_pg2<<<nb, 256, 0, stream>>>(off, ssrc, (u16*)H, att, hp, N);  // hp = pg1 out (tanh)

    // ---- output layer (fp16 H) ----
    k_gemm<128, true, true><<<gb, 256, 0, stream>>>(hs, hp, Bp[4], Bp[5], H, hs, att, gal[2], gar[2], N, 192, 128, dmode, 0, cs);
    // final mean written in-place into hs rows as f32 (row = 256B = 64 floats)
    k_edge_gat_f<<<nb, 256, 0, stream>>>(off, ssrc, (u16*)H, att, hs, (float*)hs, N);

    // H (= d_out) now dead; materialize outputs as f32.
    hipMemcpyAsync((float*)d_out, (float*)hs, (size_t)N * 64 * 4, hipMemcpyDeviceToDevice, stream);
    k_cvt<<<(N * 64 + 255) / 256, 256, 0, stream>>>(hp, (float*)d_out + (size_t)N * 64, N * 64);

    // Diagnostic: if workspace too small, out[0] reads ~100000 + MB*1000.
    if (bad) {
        float v = 100000.f + 1000.f * (float)(ws_size >> 20);
        k_tracer<<<1, 64, 0, stream>>>((float*)d_out, v);
    }
}

// Round 18
// 534.857 us; speedup vs baseline: 1.0885x; 1.0445x over previous
//
#include <hip/hip_runtime.h>

#define NN 50000
#define NE 800000
#define FBLK 8192
#define BKT 256
#define NCPY 8

typedef unsigned short u16;
typedef unsigned int u32;

typedef float f32x4 __attribute__((ext_vector_type(4)));
typedef __bf16 bf16x8 __attribute__((ext_vector_type(8)));
static_assert(sizeof(bf16x8) == 16, "bf16x8 must be 16B");

__device__ __forceinline__ float bf2f(u16 u) {
    u32 x = ((u32)u) << 16;
    return __uint_as_float(x);
}
__device__ __forceinline__ u16 f2bf(float f) {
    u32 x = __float_as_uint(f);
    u32 r = (x + 0x7fffu + ((x >> 16) & 1u)) >> 16;  // round-nearest-even
    return (u16)r;
}
__device__ __forceinline__ u32 pack2(float a, float b) {
    return (u32)f2bf(a) | ((u32)f2bf(b) << 16);
}
// fp16 (IEEE half) pack/unpack: H tensor is fp16 (2^-11 rel err vs bf16's 2^-8).
__device__ __forceinline__ u16 f2h(float f) {
    _Float16 h = (_Float16)f;
    union { _Float16 h; u16 u; } c; c.h = h;
    return c.u;
}
__device__ __forceinline__ float h2f(u16 u) {
    union { u16 u; _Float16 h; } c; c.u = u;
    return (float)c.h;
}
__device__ __forceinline__ uint4 packu4(const u16* h) {
    uint4 u;
    u.x = (u32)h[0] | ((u32)h[1] << 16);
    u.y = (u32)h[2] | ((u32)h[3] << 16);
    u.z = (u32)h[4] | ((u32)h[5] << 16);
    u.w = (u32)h[6] | ((u32)h[7] << 16);
    return u;
}
__device__ __forceinline__ float ldf(const void* p, size_t idx, int mode) {
    return mode ? bf2f(((const u16*)p)[idx]) : ((const float*)p)[idx];
}
__device__ __forceinline__ float lrelu(float x) { return x > 0.f ? x : 0.2f * x; }

// D = A.B + C ; A/B frags: 8 contiguous k per lane (k-group = lane>>4), lane&15 = row(A)/col(B)
// D: col = lane&15, row = (lane>>4)*4 + reg   [measured m89/m91]
__device__ __forceinline__ f32x4 mfma16(uint4 a, uint4 b, f32x4 c) {
    union { uint4 u; bf16x8 b; } ua, ub;
    ua.u = a; ub.u = b;
    return __builtin_amdgcn_mfma_f32_16x16x32_bf16(ua.b, ub.b, c, 0, 0, 0);
}

// ---------------- diagnostics ----------------
__global__ void k_tracer(float* out, float v) {
    if (threadIdx.x == 0 && blockIdx.x == 0) out[0] = v;
}

// ---------------- dtype detect (0 = f32 inputs, 1 = bf16 inputs) ----------------
__global__ void k_detect(const u16* __restrict__ fvs, int* __restrict__ mode) {
    __shared__ int cnt[256];
    int t = threadIdx.x;
    int bad = 0;
    for (int i = 0; i < 16; i++) {
        u16 u = fvs[(size_t)(t * 16 + i) * 2];
        int e = (u >> 7) & 0xff;
        if (e == 255 || e >= 134 || e <= 100) bad++;
    }
    cnt[t] = bad;
    __syncthreads();
    for (int d = 128; d; d >>= 1) {
        if (t < d) cnt[t] += cnt[t + d];
        __syncthreads();
    }
    if (t == 0) *mode = (cnt[0] > 2048) ? 0 : 1;
}

// ---------------- CSR build ----------------
__global__ void k_hist(const int* __restrict__ dst, int* __restrict__ cnt, int E) {
    int e = blockIdx.x * blockDim.x + threadIdx.x;
    if (e < E) atomicAdd(&cnt[dst[e]], 1);
}

// Multi-block scan, 2048 elems/block (8/thread via int4).
__global__ void k_scan1(const int* __restrict__ cnt, int* __restrict__ off,
                        int* __restrict__ bsum, int N) {
    __shared__ int wsum[4];
    int t = threadIdx.x;
    int base = blockIdx.x * 2048 + t * 8;
    int e[8];
    if (base + 8 <= N) {
        int4 v0 = *(const int4*)&cnt[base];
        int4 v1 = *(const int4*)&cnt[base + 4];
        e[0] = v0.x; e[1] = v0.y; e[2] = v0.z; e[3] = v0.w;
        e[4] = v1.x; e[5] = v1.y; e[6] = v1.z; e[7] = v1.w;
    } else {
#pragma unroll
        for (int i = 0; i < 8; i++) e[i] = (base + i < N) ? cnt[base + i] : 0;
    }
    int s = 0;
    int ps[8];
#pragma unroll
    for (int i = 0; i < 8; i++) { ps[i] = s; s += e[i]; }
    int lane = t & 63, wv = t >> 6;
    int sc = s;
#pragma unroll
    for (int o = 1; o < 64; o <<= 1) {
        int u = __shfl_up(sc, o, 64);
        if (lane >= o) sc += u;
    }
    if (lane == 63) wsum[wv] = sc;
    __syncthreads();
    int woff = 0;
    for (int w = 0; w < wv; w++) woff += wsum[w];
    int ex = woff + sc - s;   // exclusive prefix of this thread within block
#pragma unroll
    for (int i = 0; i < 8; i++) ps[i] += ex;
    if (base + 8 <= N) {
        *(int4*)&off[base] = make_int4(ps[0], ps[1], ps[2], ps[3]);
        *(int4*)&off[base + 4] = make_int4(ps[4], ps[5], ps[6], ps[7]);
    } else {
#pragma unroll
        for (int i = 0; i < 8; i++)
            if (base + i < N) off[base + i] = ps[i];
    }
    if (t == 255) bsum[blockIdx.x] = woff + sc;   // block total
}

__global__ void k_scan2(const int* __restrict__ bsum, int* __restrict__ off,
                        int N, int nb) {
    int b = blockIdx.x, t = threadIdx.x;
    int boff = 0;
    for (int i = 0; i < b; i++) boff += bsum[i];   // uniform, <=24 iters
    int base = b * 2048 + t * 8;
    if (b > 0) {
        if (base + 8 <= N) {
            int4 a = *(int4*)&off[base];
            int4 c = *(int4*)&off[base + 4];
            a.x += boff; a.y += boff; a.z += boff; a.w += boff;
            c.x += boff; c.y += boff; c.z += boff; c.w += boff;
            *(int4*)&off[base] = a;
            *(int4*)&off[base + 4] = c;
        } else {
#pragma unroll
            for (int i = 0; i < 8; i++)
                if (base + i < N) off[base + i] += boff;
        }
    }
    if (b == nb - 1 && t == 255) off[N] = boff + bsum[b];
}

// ---- CSR fill via two-pass LDS multisplit ----
__global__ void k_binit(const int* __restrict__ off, int* __restrict__ bcur, int nbk) {
    int b = threadIdx.x;
    if (b < nbk) bcur[b] = off[b * BKT];
    else if (b < 256) bcur[b] = 0;
}

__launch_bounds__(256)
__global__ void k_fillA(const int* __restrict__ src, const int* __restrict__ dst,
                        int* __restrict__ bcur, u32* __restrict__ tmp, int E) {
    __shared__ int hist[256];
    __shared__ int lbase[256];
    __shared__ int gbase[256];
    __shared__ int lcur[256];
    __shared__ u32 outrec[FBLK];
    __shared__ unsigned char bslot[FBLK];
    int t = threadIdx.x;
    int e0 = blockIdx.x * FBLK;
    int bn = min(E - e0, FBLK);
    hist[t] = 0;
    __syncthreads();
    for (int i = t; i < bn; i += 256)
        atomicAdd(&hist[dst[e0 + i] >> 8], 1);
    __syncthreads();
    if (t == 0) {
        int run = 0;
        for (int b = 0; b < 256; b++) { lbase[b] = run; run += hist[b]; }
    }
    __syncthreads();
    lcur[t] = lbase[t];
    gbase[t] = hist[t] ? atomicAdd(&bcur[t], hist[t]) : 0;
    __syncthreads();
    for (int i = t; i < bn; i += 256) {
        int d = dst[e0 + i];
        int s = src[e0 + i];
        int b = d >> 8;
        int slot = atomicAdd(&lcur[b], 1);
        outrec[slot] = (u32)s | ((u32)(d & 255) << 24);   // src < 2^24
        bslot[slot] = (unsigned char)b;
    }
    __syncthreads();
    for (int i = t; i < bn; i += 256) {
        int b = bslot[i];
        tmp[gbase[b] + (i - lbase[b])] = outrec[i];       // contiguous bucket runs
    }
}

__launch_bounds__(256)
__global__ void k_fillB(const int* __restrict__ off, const u32* __restrict__ tmp,
                        int* __restrict__ ssrc, int N) {
    __shared__ int lcur[BKT];
    __shared__ u32 outv[FBLK];
    int b = blockIdx.x, t = threadIdx.x;
    int n0 = b * BKT;
    int nn = min(N - n0, BKT);
    int nbeg = off[n0], nend = off[n0 + nn];
    int sz = nend - nbeg;
    for (int i = t; i < nn; i += 256) lcur[i] = off[n0 + i] - nbeg;
    __syncthreads();
    if (sz <= FBLK) {
        for (int i = t; i < sz; i += 256) {
            u32 r = tmp[nbeg + i];
            int slot = atomicAdd(&lcur[r >> 24], 1);
            outv[slot] = r & 0x00FFFFFFu;
        }
        __syncthreads();
        for (int i = t; i < sz; i += 256)
            ssrc[nbeg + i] = (int)outv[i];
    } else {  // bucket overflow fallback (correctness only)
        for (int i = t; i < sz; i += 256) {
            u32 r = tmp[nbeg + i];
            int slot = atomicAdd(&lcur[r >> 24], 1);
            ssrc[nbeg + slot] = (int)(r & 0x00FFFFFFu);
        }
    }
}

// ---------------- init: hp = bf16(pos) ----------------
__global__ void k_init(const void* __restrict__ pos, u16* __restrict__ hp,
                       const int* __restrict__ dmode, int n64) {
    int i = blockIdx.x * blockDim.x + threadIdx.x;
    if (i >= n64) return;
    int mode = *dmode;
    hp[i] = mode ? ((const u16*)pos)[i] : f2bf(((const float*)pos)[i]);
}

// ---------------- hp (bf16) -> f32 ----------------
__global__ void k_cvt(const u16* __restrict__ in, float* __restrict__ out, int n) {
    int i = blockIdx.x * blockDim.x + threadIdx.x;
    if (i < n) out[i] = bf2f(in[i]);
}

// ---------------- weight pre-split: W -> packed {hi,lo} bf16 (copy 0 only) ----------------
struct PWArgs {
    const void* src[8];
    u16* dst[8];
    int K[8];
    int BM[8];
};

__global__ void k_prepw(PWArgs a, const int* __restrict__ dmode) {
    int mode = *dmode;
    int g = blockIdx.x * blockDim.x + threadIdx.x;
    int stride = gridDim.x * blockDim.x;
    for (int m = 0; m < 8; m++) {
        int bm = a.BM[m];
        int bmsh = (bm == 128) ? 7 : 6;
        int n = a.K[m] * bm;
        u16* d = a.dst[m];
        const void* s = a.src[m];
        for (int i = g; i < n; i += stride) {
            int k = i >> bmsh, c = i & (bm - 1);
            float v = mode ? bf2f(((const u16*)s)[i]) : ((const float*)s)[i];
            u16 hi = f2bf(v);
            u16 lo = f2bf(v - bf2f(hi));
            size_t o = ((size_t)((k >> 5) * 2) * bm + c) * 32 + (k & 31);
            d[o] = hi;
            d[o + (size_t)bm * 32] = lo;
        }
    }
}

// Vectorized clone of packed-weight copy 0 into copies 1..NCPY-1 (uint4 = 16B units).
__global__ void k_wcopy(u32* __restrict__ wpk, int nq, int cq) {
    int i = blockIdx.x * blockDim.x + threadIdx.x;
    if (i >= nq * (NCPY - 1)) return;
    int cc = i / nq + 1;
    int q = i - (cc - 1) * nq;
    uint4* p = (uint4*)wpk;
    p[(size_t)cc * cq + q] = p[q];
}

// ---------------- MFMA GEMM body (device fn; bid = logical block index) ----------------
// Round-8 structure + XCD-aligned B replication (copy = raw blockIdx & 7).
template <int BM, bool HASB2, bool C1H>
__device__ __forceinline__ void gemm_body(
        int bid, int cpy, const void* A1, const u16* __restrict__ A2,
        const u16* __restrict__ B1p, const u16* __restrict__ B2p,
        void* __restrict__ C1, u16* C2, float* __restrict__ att,
        const void* __restrict__ al, const void* __restrict__ ar,
        int N, int K, int s1, int mode, int a1_input, int cstride) {
    constexpr int NR = BM / 32;
    constexpr int NMAT = HASB2 ? 2 : 1;

    const int a1f32 = (a1_input && mode == 0) ? 1 : 0;
    const int bsplit = (mode == 0) ? 1 : 0;

    const int tid = threadIdx.x;
    const int lane = tid & 63;
    const int wid = tid >> 6;
    const int l15 = lane & 15, l4 = lane >> 4;
    const int r0 = bid * 64;
    const int wrow0 = (wid >> 1) * 32;
    const int wcol0 = (wid & 1) * (BM / 2);
    const int ko = l4 * 8;

    const size_t coff = (size_t)cpy * (size_t)cstride;
    const u16* b1 = B1p + coff;
    const u16* b2 = HASB2 ? (B2p + coff) : nullptr;

    int frow[2];
#pragma unroll
    for (int m = 0; m < 2; m++) {
        int r = r0 + wrow0 + m * 16 + l15;
        frow[m] = r < N ? r : N - 1;
    }

    f32x4 acc[NMAT][2][NR];
    const f32x4 fz = {0.f, 0.f, 0.f, 0.f};
#pragma unroll
    for (int m2 = 0; m2 < NMAT; m2++)
#pragma unroll
        for (int m = 0; m < 2; m++)
#pragma unroll
            for (int n = 0; n < NR; n++) acc[m2][m][n] = fz;

    const int NKT = K >> 5;
    const int rot = (int)((u32)(bid >> 3) % (u32)NKT);   // desync within an XCD
    for (int tt = 0; tt < NKT; tt++) {
        int kt = tt + rot;
        if (kt >= NKT) kt -= NKT;
        const int k0 = kt << 5;
        const int doAlo = (a1f32 && k0 < 128) ? 1 : 0;

        uint4 ah[2], alo[2];
#pragma unroll
        for (int m = 0; m < 2; m++) {
            if (k0 >= 128) {               // A2 region (always bf16, stride 64)
                ah[m] = *(const uint4*)(A2 + (size_t)frow[m] * 64 + (k0 - 128) + ko);
            } else if (!a1f32) {           // A1 bf16
                ah[m] = *(const uint4*)((const u16*)A1 + (size_t)frow[m] * s1 + k0 + ko);
            } else {                       // A1 f32: load 32B, split hi/lo in regs
                const float* p = (const float*)A1 + (size_t)frow[m] * s1 + k0 + ko;
                union { uint4 u[2]; float f[8]; } fa;
                fa.u[0] = *(const uint4*)p;
                fa.u[1] = *(const uint4*)(p + 4);
                u16 hi[8], lo[8];
#pragma unroll
                for (int i = 0; i < 8; i++) {
                    hi[i] = f2bf(fa.f[i]);
                    lo[i] = f2bf(fa.f[i] - bf2f(hi[i]));   // exact residual (Sterbenz)
                }
                ah[m] = packu4(hi);
                alo[m] = packu4(lo);
            }
        }

        const size_t bbase = ((size_t)kt * 2) * BM * 32 + (size_t)l4 * 8;
#pragma unroll
        for (int n = 0; n < NR; n++) {
            const int c = wcol0 + n * 16 + l15;
            const size_t co = (size_t)c * 32;
#pragma unroll
            for (int m2 = 0; m2 < NMAT; m2++) {
                const u16* bp = (m2 == 0 ? b1 : b2) + bbase + co;
                uint4 bh = *(const uint4*)bp;
#pragma unroll
                for (int m = 0; m < 2; m++)
                    acc[m2][m][n] = mfma16(ah[m], bh, acc[m2][m][n]);
                if (bsplit) {
                    uint4 bl = *(const uint4*)(bp + (size_t)BM * 32);
#pragma unroll
                    for (int m = 0; m < 2; m++)
                        acc[m2][m][n] = mfma16(ah[m], bl, acc[m2][m][n]);
                }
                if (doAlo) {
#pragma unroll
                    for (int m = 0; m < 2; m++)
                        acc[m2][m][n] = mfma16(alo[m], bh, acc[m2][m][n]);
                }
            }
        }
    }

    __syncthreads();   // in-place safety: all block A-reads done before C2 writes

    float alc[NR], arc[NR];
#pragma unroll
    for (int n = 0; n < NR; n++) {
        int c = wcol0 + n * 16 + l15;
        alc[n] = ldf(al, c, mode);
        arc[n] = ldf(ar, c, mode);
    }
    const int hc = wid & 1;
#pragma unroll
    for (int m = 0; m < 2; m++) {
#pragma unroll
        for (int r = 0; r < 4; r++) {
            const int gr = r0 + wrow0 + m * 16 + l4 * 4 + r;
            float el = 0.f, er = 0.f;
#pragma unroll
            for (int n = 0; n < NR; n++) {
                float v = acc[0][m][n][r];
                el = fmaf(v, alc[n], el);
                er = fmaf(v, arc[n], er);
            }
#pragma unroll
            for (int o = 1; o <= 8; o <<= 1) {   // reduce the 16 col-lanes (same row)
                el += __shfl_xor(el, o, 64);
                er += __shfl_xor(er, o, 64);
            }
            if (gr < N) {
#pragma unroll
                for (int n = 0; n < NR; n++) {
                    const int c = wcol0 + n * 16 + l15;
                    float v = acc[0][m][n][r];
                    if constexpr (C1H)
                        ((u16*)C1)[(size_t)gr * BM + c] = f2h(v);
                    else
                        ((float*)C1)[(size_t)gr * BM + c] = v;
                    if constexpr (HASB2)
                        C2[(size_t)gr * 128 + c] = f2bf(acc[1][m][n][r]);
                }
                if (l15 == 0) {
                    att[(size_t)gr * 4 + hc] = el;
                    att[(size_t)gr * 4 + 2 + hc] = er;
                }
            }
        }
    }
}

// Fused launch: gat GEMM (blocks < gbGat) + pg GEMM (rest) — data-independent,
// both ~10%-utilized latency-bound, so co-residency hides the pg GEMM.
__launch_bounds__(256, 4)
__global__ void k_gemm_fused(const void* gA1, const u16* gA2,
                             const u16* gB1, const u16* gB2,
                             void* gC1, u16* gC2, float* gatt,
                             const void* gal, const void* gar, int gK, int gs1, int ga1,
                             const void* pA1, const u16* pB1,
                             void* pC1, float* patt,
                             const void* pal, const void* par,
                             int N, const int* __restrict__ dmode, int cstride, int gbGat) {
    int mode = *dmode;
    int cpy = blockIdx.x & (NCPY - 1);   // XCD-aligned (xcd = blockIdx % 8)
    if (blockIdx.x < gbGat)
        gemm_body<128, true, true>(blockIdx.x, cpy, gA1, gA2, gB1, gB2, gC1, gC2,
                                   gatt, gal, gar, N, gK, gs1, mode, ga1, cstride);
    else
        gemm_body<64, false, true>(blockIdx.x - gbGat, cpy, pA1, nullptr, pB1, nullptr,
                                   pC1, nullptr, patt, pal, par, N, 64, 64, mode, 0, cstride);
}

// Output-layer GEMM (gat only)
__launch_bounds__(256, 4)
__global__ void k_gemm_gat(const void* A1, const u16* A2,
                           const u16* B1, const u16* B2,
                           void* C1, u16* C2, float* att,
                           const void* al, const void* ar,
                           int N, int K, int s1, const int* __restrict__ dmode,
                           int a1_input, int cstride) {
    int mode = *dmode;
    int cpy = blockIdx.x & (NCPY - 1);
    gemm_body<128, true, true>(blockIdx.x, cpy, A1, A2, B1, B2, C1, C2, att,
                               al, ar, N, K, s1, mode, a1_input, cstride);
}

// ---------------- edge aggregation bodies ----------------
__device__ void edge_gat2_body(int bid, const int* __restrict__ off,
                               const int* __restrict__ ssrc,
                               const u16* __restrict__ h, const float* __restrict__ att,
                               const u16* __restrict__ res, u16* __restrict__ outf, int N) {
    __shared__ float pbuf[4][2][64];
    __shared__ int sbuf[4][64];
    int wv = threadIdx.x >> 6;
    int node = bid * 4 + wv;
    int lane = threadIdx.x & 63;
    if (node >= N) return;
    const int hd = lane >> 5;
    int beg = off[node], end = off[node + 1];
    float4 a4 = *(const float4*)&att[(size_t)node * 4];
    float er0 = a4.z, er1 = a4.w;
    float m0 = -1e30f, m1 = -1e30f, d0 = 0.f, d1 = 0.f, O0 = 0.f, O1 = 0.f;
    for (int c = beg; c < end; c += 64) {
        int cn = min(end - c, 64);
        int s = 0;
        float x0 = -1e30f, x1 = -1e30f;
        if (lane < cn) {
            s = ssrc[c + lane];
            float2 e = *(const float2*)&att[(size_t)s * 4];
            x0 = lrelu(e.x + er0);
            x1 = lrelu(e.y + er1);
        }
        float cm0 = x0, cm1 = x1;
#pragma unroll
        for (int o = 32; o; o >>= 1) {
            cm0 = fmaxf(cm0, __shfl_xor(cm0, o, 64));
            cm1 = fmaxf(cm1, __shfl_xor(cm1, o, 64));
        }
        float nm0 = fmaxf(m0, cm0), nm1 = fmaxf(m1, cm1);
        float p0 = (lane < cn) ? __expf(x0 - nm0) : 0.f;
        float p1 = (lane < cn) ? __expf(x1 - nm1) : 0.f;
        float cd0 = p0, cd1 = p1;
#pragma unroll
        for (int o = 32; o; o >>= 1) {
            cd0 += __shfl_xor(cd0, o, 64);
            cd1 += __shfl_xor(cd1, o, 64);
        }
        float sc0 = __expf(m0 - nm0), sc1 = __expf(m1 - nm1);
        d0 = d0 * sc0 + cd0; d1 = d1 * sc1 + cd1;
        float sch = hd ? sc1 : sc0;
        O0 *= sch; O1 *= sch;
        m0 = nm0; m1 = nm1;
        pbuf[wv][0][lane] = p0;
        pbuf[wv][1][lane] = p1;
        sbuf[wv][lane] = s;
        const float* pb = pbuf[wv][hd];
        int j = 0;
        for (; j + 7 < cn; j += 8) {     // 8 loads in flight
            u32 w[8];
#pragma unroll
            for (int t = 0; t < 8; t++)
                w[t] = *(const u32*)&h[(size_t)sbuf[wv][j + t] * 128 + 2 * lane];
#pragma unroll
            for (int t = 0; t < 8; t++) {
                float q = pb[j + t];
                O0 += q * h2f((u16)w[t]);
                O1 += q * h2f((u16)(w[t] >> 16));
            }
        }
        if (j + 3 < cn) {
            u32 w[4];
#pragma unroll
            for (int t = 0; t < 4; t++)
                w[t] = *(const u32*)&h[(size_t)sbuf[wv][j + t] * 128 + 2 * lane];
#pragma unroll
            for (int t = 0; t < 4; t++) {
                float q = pb[j + t];
                O0 += q * h2f((u16)w[t]);
                O1 += q * h2f((u16)(w[t] >> 16));
            }
            j += 4;
        }
        for (; j < cn; j++) {
            u32 w = *(const u32*)&h[(size_t)sbuf[wv][j] * 128 + 2 * lane];
            float q = pb[j];
            O0 += q * h2f((u16)w);
            O1 += q * h2f((u16)(w >> 16));
        }
    }
    float dd = hd ? d1 : d0;
    float o0 = (end > beg) ? O0 / dd : 0.f;
    float o1 = (end > beg) ? O1 / dd : 0.f;
    u32 rv = *(const u32*)&res[(size_t)node * 128 + 2 * lane];
    float a0 = o0 + bf2f((u16)rv);
    float a1 = o1 + bf2f((u16)(rv >> 16));
    a0 = a0 > 0.f ? a0 : (__expf(a0) - 1.f);  // elu
    a1 = a1 > 0.f ? a1 : (__expf(a1) - 1.f);
    *(u32*)&outf[(size_t)node * 128 + 2 * lane] = pack2(a0, a1);
}

__device__ void edge_pg2_body(int bid, const int* __restrict__ off,
                              const int* __restrict__ ssrc,
                              const u16* __restrict__ h, const float* __restrict__ att,
                              u16* __restrict__ hp, int N) {
    __shared__ float pbuf2[4][2][64];
    __shared__ int sbuf2[4][64];
    int wv = threadIdx.x >> 6;
    int node = bid * 4 + wv;
    int lane = threadIdx.x & 63;
    if (node >= N) return;
    const int par = lane >> 5;
    const int i = lane & 31;
    const int hd = i >> 4;
    int beg = off[node], end = off[node + 1];
    float4 a4 = *(const float4*)&att[(size_t)node * 4];
    float er0 = a4.z, er1 = a4.w;
    float m0 = -1e30f, m1 = -1e30f, d0 = 0.f, d1 = 0.f, O0 = 0.f, O1 = 0.f;
    for (int c = beg; c < end; c += 64) {
        int cn = min(end - c, 64);
        int s = 0;
        float x0 = -1e30f, x1 = -1e30f;
        if (lane < cn) {
            s = ssrc[c + lane];
            float2 e = *(const float2*)&att[(size_t)s * 4];
            x0 = lrelu(e.x + er0);
            x1 = lrelu(e.y + er1);
        }
        float cm0 = x0, cm1 = x1;
#pragma unroll
        for (int o = 32; o; o >>= 1) {
            cm0 = fmaxf(cm0, __shfl_xor(cm0, o, 64));
            cm1 = fmaxf(cm1, __shfl_xor(cm1, o, 64));
        }
        float nm0 = fmaxf(m0, cm0), nm1 = fmaxf(m1, cm1);
        float p0 = (lane < cn) ? __expf(x0 - nm0) : 0.f;
        float p1 = (lane < cn) ? __expf(x1 - nm1) : 0.f;
        float cd0 = p0, cd1 = p1;
#pragma unroll
        for (int o = 32; o; o >>= 1) {
            cd0 += __shfl_xor(cd0, o, 64);
            cd1 += __shfl_xor(cd1, o, 64);
        }
        float sc0 = __expf(m0 - nm0), sc1 = __expf(m1 - nm1);
        d0 = d0 * sc0 + cd0; d1 = d1 * sc1 + cd1;
        float sch = hd ? sc1 : sc0;
        O0 *= sch; O1 *= sch;
        m0 = nm0; m1 = nm1;
        pbuf2[wv][0][lane] = p0;
        pbuf2[wv][1][lane] = p1;
        sbuf2[wv][lane] = s;
        const float* pb = pbuf2[wv][hd];
        int j = par;
        for (; j + 14 < cn; j += 16) {   // 8 edges of my parity, 8 loads in flight
            u32 w[8];
#pragma unroll
            for (int t = 0; t < 8; t++)
                w[t] = *(const u32*)&h[(size_t)sbuf2[wv][j + 2 * t] * 64 + 2 * i];
#pragma unroll
            for (int t = 0; t < 8; t++) {
                float q = pb[j + 2 * t];
                O0 += q * h2f((u16)w[t]);
                O1 += q * h2f((u16)(w[t] >> 16));
            }
        }
        if (j + 6 < cn) {                // 4 edges of my parity
            u32 w[4];
#pragma unroll
            for (int t = 0; t < 4; t++)
                w[t] = *(const u32*)&h[(size_t)sbuf2[wv][j + 2 * t] * 64 + 2 * i];
#pragma unroll
            for (int t = 0; t < 4; t++) {
                float q = pb[j + 2 * t];
                O0 += q * h2f((u16)w[t]);
                O1 += q * h2f((u16)(w[t] >> 16));
            }
            j += 8;
        }
        for (; j < cn; j += 2) {
            u32 w = *(const u32*)&h[(size_t)sbuf2[wv][j] * 64 + 2 * i];
            float q = pb[j];
            O0 += q * h2f((u16)w);
            O1 += q * h2f((u16)(w >> 16));
        }
    }
    O0 += __shfl_xor(O0, 32, 64);        // combine edge parities
    O1 += __shfl_xor(O1, 32, 64);
    if (lane < 32) {
        float dd = hd ? d1 : d0;
        float o0 = (end > beg) ? O0 / dd : 0.f;
        float o1 = (end > beg) ? O1 / dd : 0.f;
        u32 rv = *(const u32*)&hp[(size_t)node * 64 + 2 * i];
        float a0 = tanhf(o0 + bf2f((u16)rv));
        float a1 = tanhf(o1 + bf2f((u16)(rv >> 16)));
        *(u32*)&hp[(size_t)node * 64 + 2 * i] = pack2(a0, a1);
    }
}

// Fused edge launch: gat (blocks < nbGat) + pg (rest) — independent paths.
__global__ void k_edge_fused(const int* __restrict__ off, const int* __restrict__ ssrc,
                             const u16* __restrict__ hg, const float* __restrict__ attg,
                             const u16* __restrict__ res, u16* __restrict__ outf,
                             const u16* __restrict__ hpg, const float* __restrict__ attp,
                             u16* __restrict__ hp, int N, int nbGat) {
    if (blockIdx.x < nbGat)
        edge_gat2_body(blockIdx.x, off, ssrc, hg, attg, res, outf, N);
    else
        edge_pg2_body(blockIdx.x - nbGat, off, ssrc, hpg, attp, hp, N);
}

// Final layer (mean over heads): fp16 H, edge-parity split, gather unroll-8.
__global__ void k_edge_gat_f(const int* __restrict__ off, const int* __restrict__ ssrc,
                             const u16* __restrict__ h, const float* __restrict__ att,
                             const u16* __restrict__ res, float* __restrict__ outs, int N) {
    __shared__ float pbuf[4][2][64];
    __shared__ int sbuf[4][64];
    int wv = threadIdx.x >> 6;
    int node = blockIdx.x * 4 + wv;
    int lane = threadIdx.x & 63;
    if (node >= N) return;
    const int par = lane >> 5;
    const int i = lane & 31;
    const int hd = i >> 4;
    int beg = off[node], end = off[node + 1];
    float4 a4 = *(const float4*)&att[(size_t)node * 4];
    float er0 = a4.z, er1 = a4.w;
    float m0 = -1e30f, m1 = -1e30f, d0 = 0.f, d1 = 0.f;
    float O[4] = {0.f, 0.f, 0.f, 0.f};
    for (int c = beg; c < end; c += 64) {
        int cn = min(end - c, 64);
        int s = 0;
        float x0 = -1e30f, x1 = -1e30f;
        if (lane < cn) {
            s = ssrc[c + lane];
            float2 e = *(const float2*)&att[(size_t)s * 4];
            x0 = lrelu(e.x + er0);
            x1 = lrelu(e.y + er1);
        }
        float cm0 = x0, cm1 = x1;
#pragma unroll
        for (int o = 32; o; o >>= 1) {
            cm0 = fmaxf(cm0, __shfl_xor(cm0, o, 64));
            cm1 = fmaxf(cm1, __shfl_xor(cm1, o, 64));
        }
        float nm0 = fmaxf(m0, cm0), nm1 = fmaxf(m1, cm1);
        float p0 = (lane < cn) ? __expf(x0 - nm0) : 0.f;
        float p1 = (lane < cn) ? __expf(x1 - nm1) : 0.f;
        float cd0 = p0, cd1 = p1;
#pragma unroll
        for (int o = 32; o; o >>= 1) {
            cd0 += __shfl_xor(cd0, o, 64);
            cd1 += __shfl_xor(cd1, o, 64);
        }
        float sc0 = __expf(m0 - nm0), sc1 = __expf(m1 - nm1);
        d0 = d0 * sc0 + cd0; d1 = d1 * sc1 + cd1;
        float sch = hd ? sc1 : sc0;
#pragma unroll
        for (int k = 0; k < 4; k++) O[k] *= sch;
        m0 = nm0; m1 = nm1;
        pbuf[wv][0][lane] = p0;
        pbuf[wv][1][lane] = p1;
        sbuf[wv][lane] = s;
        const float* pb = pbuf[wv][hd];
        int j = par;
        for (; j + 14 < cn; j += 16) {   // 8 edges of my parity, 8 loads in flight
            uint2 w[8];
#pragma unroll
            for (int t = 0; t < 8; t++)
                w[t] = *(const uint2*)&h[(size_t)sbuf[wv][j + 2 * t] * 128 + 4 * i];
#pragma unroll
            for (int t = 0; t < 8; t++) {
                float q = pb[j + 2 * t];
                O[0] += q * h2f((u16)w[t].x);
                O[1] += q * h2f((u16)(w[t].x >> 16));
                O[2] += q * h2f((u16)w[t].y);
                O[3] += q * h2f((u16)(w[t].y >> 16));
            }
        }
        if (j + 6 < cn) {                // 4 edges of my parity
            uint2 w[4];
#pragma unroll
            for (int t = 0; t < 4; t++)
                w[t] = *(const uint2*)&h[(size_t)sbuf[wv][j + 2 * t] * 128 + 4 * i];
#pragma unroll
            for (int t = 0; t < 4; t++) {
                float q = pb[j + 2 * t];
                O[0] += q * h2f((u16)w[t].x);
                O[1] += q * h2f((u16)(w[t].x >> 16));
                O[2] += q * h2f((u16)w[t].y);
                O[3] += q * h2f((u16)(w[t].y >> 16));
            }
            j += 8;
        }
        for (; j < cn; j += 2) {
            uint2 w = *(const uint2*)&h[(size_t)sbuf[wv][j] * 128 + 4 * i];
            float q = pb[j];
            O[0] += q * h2f((u16)w.x);
            O[1] += q * h2f((u16)(w.x >> 16));
            O[2] += q * h2f((u16)w.y);
            O[3] += q * h2f((u16)(w.y >> 16));
        }
    }
#pragma unroll
    for (int k = 0; k < 4; k++) O[k] += __shfl_xor(O[k], 32, 64);  // combine parities
    float dd = hd ? d1 : d0;
    uint2 rv = *(const uint2*)&res[(size_t)node * 128 + 4 * i];
    float a[4];
    a[0] = bf2f((u16)rv.x);
    a[1] = bf2f((u16)(rv.x >> 16));
    a[2] = bf2f((u16)rv.y);
    a[3] = bf2f((u16)(rv.y >> 16));
#pragma unroll
    for (int k = 0; k < 4; k++) {
        float o = (end > beg) ? O[k] / dd : 0.f;
        float v = o + a[k];
        a[k] = v > 0.f ? v : (__expf(v) - 1.f);  // elu
    }
    float b[4];
#pragma unroll
    for (int k = 0; k < 4; k++) b[k] = __shfl_xor(a[k], 16, 64);  // partner head
    if (lane < 16)
        *(float4*)&outs[(size_t)node * 64 + 4 * i] =
            make_float4(0.5f * (a[0] + b[0]), 0.5f * (a[1] + b[1]),
                        0.5f * (a[2] + b[2]), 0.5f * (a[3] + b[3]));
}

// ---------------- launch ----------------
extern "C" void kernel_launch(void* const* d_in, const int* in_sizes, int n_in,
                              void* d_out, int out_size, void* d_ws, size_t ws_size,
                              hipStream_t stream) {
    const int N = NN, E = NE;
    const void* fvs = d_in[0];
    const void* pos = d_in[1];
    const int* src = (const int*)d_in[2];
    const int* dst = (const int*)d_in[3];
    const void* gW[3]  = {d_in[4],  d_in[8],  d_in[12]};
    const void* gal[3] = {d_in[5],  d_in[9],  d_in[13]};
    const void* gar[3] = {d_in[6],  d_in[10], d_in[14]};
    const void* grW[3] = {d_in[7],  d_in[11], d_in[15]};
    const void* pW[2]  = {d_in[16], d_in[19]};
    const void* pal[2] = {d_in[17], d_in[20]};
    const void* par[2] = {d_in[18], d_in[21]};

    // packed weight geometry (u16 counts)
    const size_t GSZ = (size_t)192 * 128 * 2;   // u16 per gat matrix (hi+lo)
    const size_t PSZ = (size_t)64 * 64 * 2;
    const size_t CS  = 6 * GSZ + 2 * PSZ;       // u16 per copy (16B-divisible)

    // ---- workspace layout (wrap-safe) ----
    auto al256 = [](size_t b) { return (b + 255) & ~(size_t)255; };
    size_t sz_dmode = al256(4);
    size_t sz_bsum  = al256(32 * 4);
    size_t sz_bcur  = al256(256 * 4);
    size_t sz_att   = al256((size_t)N * 4 * 4);   // gat att; also hosts cnt during CSR build
    size_t sz_att2  = al256((size_t)N * 4 * 4);   // pg att (fused launches need both live)
    size_t sz_off   = al256((size_t)(N + 1) * 4);
    size_t sz_ssrc  = al256((size_t)E * 4);
    size_t sz_hs    = al256((size_t)N * 128 * 2);
    size_t sz_hp    = al256((size_t)N * 64 * 2);
    size_t sz_wpk   = al256(CS * NCPY * 2);       // NCPY replicated copies
    size_t need = sz_dmode + sz_bsum + sz_bcur + sz_att + sz_att2 + sz_off + sz_ssrc
                + sz_hs + sz_hp + sz_wpk;
    int bad = (need > ws_size) ? 1 : 0;

    size_t cur = 0;
    auto alloc = [&](size_t bytes) {
        if (cur + bytes > ws_size) cur = 0;
        char* p = (char*)d_ws + cur;
        if (bytes <= ws_size) cur += bytes;
        return p;
    };
    int* dmode  = (int*)alloc(sz_dmode);
    int* bsum   = (int*)alloc(sz_bsum);
    int* bcur   = (int*)alloc(sz_bcur);
    float* attg = (float*)alloc(sz_att);
    float* attp = (float*)alloc(sz_att2);
    int* off    = (int*)alloc(sz_off);
    int* ssrc   = (int*)alloc(sz_ssrc);
    u16* hs     = (u16*)alloc(sz_hs);
    u16* hp     = (u16*)alloc(sz_hp);
    u16* wpk    = (u16*)alloc(sz_wpk);

    // packed weight slots within copy 0: [gW0, grW0, gW1, grW1, gW2, grW2, pW0, pW1]
    u16* Bp[8];
    for (int m = 0; m < 6; m++) Bp[m] = wpk + (size_t)m * GSZ;
    Bp[6] = wpk + 6 * GSZ;
    Bp[7] = Bp[6] + PSZ;

    // cnt aliases attg; tmp (binned edges, 3.2MB) aliases hs (dead before first GEMM).
    int* cnt = (int*)attg;
    u32* tmp = (u32*)hs;

    // d_out hosts both H tensors while live: gat fp16 [N,128] (12.8MB) then pg fp16
    // [N,64] (6.4MB); both dead before the final outputs are materialized.
    u16* Hg = (u16*)d_out;
    u16* Hp = (u16*)d_out + (size_t)N * 128;

    hipMemsetAsync(cnt, 0, (size_t)N * 4, stream);

    k_detect<<<1, 256, 0, stream>>>((const u16*)fvs, dmode);

    PWArgs pwa;
    pwa.src[0] = gW[0]; pwa.src[1] = grW[0];
    pwa.src[2] = gW[1]; pwa.src[3] = grW[1];
    pwa.src[4] = gW[2]; pwa.src[5] = grW[2];
    pwa.src[6] = pW[0]; pwa.src[7] = pW[1];
    for (int m = 0; m < 8; m++) {
        pwa.dst[m] = Bp[m];
        pwa.K[m] = (m < 6) ? 192 : 64;
        pwa.BM[m] = (m < 6) ? 128 : 64;
    }
    k_prepw<<<64, 256, 0, stream>>>(pwa, dmode);
    {
        int nq = (int)(CS / 8);            // uint4 per copy
        int tot = nq * (NCPY - 1);
        k_wcopy<<<(tot + 255) / 256, 256, 0, stream>>>((u32*)wpk, nq, nq);
    }

    int eb = (E + 255) / 256;
    int nbS = (N + 2047) / 2048;
    int nbk = (N + BKT - 1) / BKT;
    k_hist<<<eb, 256, 0, stream>>>(dst, cnt, E);
    k_scan1<<<nbS, 256, 0, stream>>>(cnt, off, bsum, N);
    k_scan2<<<nbS, 256, 0, stream>>>(bsum, off, N, nbS);
    k_binit<<<1, 256, 0, stream>>>(off, bcur, nbk);
    k_fillA<<<(E + FBLK - 1) / FBLK, 256, 0, stream>>>(src, dst, bcur, tmp, E);
    k_fillB<<<nbk, 256, 0, stream>>>(off, tmp, ssrc, N);

    k_init<<<(N * 64 + 255) / 256, 256, 0, stream>>>(pos, hp, dmode, N * 64);

    int gb = (N + 63) / 64;
    int nb = (N + 3) / 4;
    int cs = (int)CS;

    // ---- layer 0 (fused gat+pg GEMM, then fused edge) ----
    k_gemm_fused<<<2 * gb, 256, 0, stream>>>(
        fvs, hp, Bp[0], Bp[1], Hg, hs, attg, gal[0], gar[0], 192, 128, 1,
        hp, Bp[6], Hp, attp, pal[0], par[0], N, dmode, cs, gb);
    k_edge_fused<<<2 * nb, 256, 0, stream>>>(off, ssrc, Hg, attg, hs, hs,
                                             Hp, attp, hp, N, nb);

    // ---- layer 1 ----
    k_gemm_fused<<<2 * gb, 256, 0, stream>>>(
        hs, hp, Bp[2], Bp[3], Hg, hs, attg, gal[1], gar[1], 192, 128, 0,
        hp, Bp[7], Hp, attp, pal[1], par[1], N, dmode, cs, gb);
    k_edge_fused<<<2 * nb, 256, 0, stream>>>(off, ssrc, Hg, attg, hs, hs,
                                             Hp, attp, hp, N, nb);

    // ---- output layer (gat only) ----
    k_gemm_gat<<<gb, 256, 0, stream>>>(hs, hp, Bp[4], Bp[5], Hg, hs, attg,
                                       gal[2], gar[2], N, 192, 128, dmode, 0, cs);
    // final mean written in-place into hs rows as f32 (row = 256B = 64 floats)
    k_edge_gat_f<<<nb, 256, 0, stream>>>(off, ssrc, Hg, attg, hs, (float*)hs, N);

    // H regions (in d_out) now dead; materialize outputs as f32.
    hipMemcpyAsync((float*)d_out, (float*)hs, (size_t)N * 64 * 4, hipMemcpyDeviceToDevice, stream);
    k_cvt<<<(N * 64 + 255) / 256, 256, 0, stream>>>(hp, (float*)d_out + (size_t)N * 64, N * 64);

    // Diagnostic: if workspace too small, out[0] reads ~100000 + MB*1000.
    if (bad) {
        float v = 100000.f + 1000.f * (float)(ws_size >> 20);
        k_tracer<<<1, 64, 0, stream>>>((float*)d_out, v);
    }
}